// Round 12
// baseline (190.712 us; speedup 1.0000x reference)
//
#include <hip/hip_runtime.h>

#define L_SEQ 1024
#define NB 32
#define NH 8
#define NE 64
#define TOPK 6

// LDS geometry: 16 data planes (8 series x {re,im}) + twiddle table (512-entry).
// Plane: 1024 floats stored as 32 groups of 32 at stride 36 (12.5% pad).
// 16*1152*4B + 1088*4B = 78,080 B -> 2 blocks/CU.
#define PS   1152
#define TBO  (16 * PS)            // table offset: TC[544] then TS[544]
#define PHYS(L)  (36 * ((L) >> 5) + ((L) & 31))
#define TPHYS(E) ((E) + ((E) >> 4))
#define LDS_FLOATS (TBO + 1088)   // 19,520 floats = 78,080 B

// W16^j = (cos(pi j/8), sin(pi j/8)), j = 0..3 (compile-time twiddle steps)
constexpr float K16C[4] = {1.f, 0.92387953f, 0.70710678f, 0.38268343f};
constexpr float K16S[4] = {0.f, 0.38268343f, 0.70710678f, 0.92387953f};

// ---------------------------------------------------------------------------
// permlane*_swap(x, x) semantics (CDNA4, corrected round 12 — round 11 had
// lo/hi REVERSED -> absmax 5.48):
//   vdst' (t.x) = x[lane & ~D]  (LOW-half broadcast)
//   vsrc' (t.y) = x[lane |  D]  (HIGH-half broadcast)
// because the instruction exchanges vdst.hi-rows with vsrc.lo-rows.
// ---------------------------------------------------------------------------
__device__ __forceinline__ void swap32(float x, float& lo, float& hi)
{
#if __has_builtin(__builtin_amdgcn_permlane32_swap)
    typedef unsigned uv2 __attribute__((ext_vector_type(2)));
    const uv2 t = __builtin_amdgcn_permlane32_swap(__float_as_uint(x), __float_as_uint(x), false, false);
    lo = __uint_as_float(t.x);   // value at lane & ~32
    hi = __uint_as_float(t.y);   // value at lane | 32
#else
    const float p = __shfl_xor(x, 32, 64);
    const bool up = (threadIdx.x & 32) != 0;
    lo = up ? p : x;
    hi = up ? x : p;
#endif
}

__device__ __forceinline__ void swap16(float x, float& lo, float& hi)
{
#if __has_builtin(__builtin_amdgcn_permlane16_swap)
    typedef unsigned uv2 __attribute__((ext_vector_type(2)));
    const uv2 t = __builtin_amdgcn_permlane16_swap(__float_as_uint(x), __float_as_uint(x), false, false);
    lo = __uint_as_float(t.x);   // value at lane & ~16
    hi = __uint_as_float(t.y);   // value at lane | 16
#else
    const float p = __shfl_xor(x, 16, 64);
    const bool up = (threadIdx.x & 16) != 0;
    lo = up ? p : x;
    hi = up ? x : p;
#endif
}

// radix-4 fused butterfly (two DIF levels M, M/2) on named scalars xr#/xi#.
#define BTF4F(A,B,C,D) { \
    const float t0r = xr##A + xr##C, t0i = xi##A + xi##C; \
    const float d2r = xr##A - xr##C, d2i = xi##A - xi##C; \
    const float t2r = d2r*w1r - d2i*w1i, t2i = d2i*w1r + d2r*w1i; \
    const float t1r = xr##B + xr##D, t1i = xi##B + xi##D; \
    const float d3r = xr##B - xr##D, d3i = xi##B - xi##D; \
    const float m3r = d3r*w1r - d3i*w1i, m3i = d3i*w1r + d3r*w1i; \
    const float t3r = m3i, t3i = -m3r; \
    const float a0r = t0r + t1r, a0i = t0i + t1i; \
    const float a1r = t0r - t1r, a1i = t0i - t1i; \
    const float a2r = t2r + t3r, a2i = t2i + t3i; \
    const float a3r = t2r - t3r, a3i = t2i - t3i; \
    xr##A = a0r; xi##A = a0i; \
    xr##B = a1r*w3r - a1i*w3i; xi##B = a1i*w3r + a1r*w3i; \
    xr##C = a2r; xi##C = a2i; \
    xr##D = a3r*w3r - a3i*w3i; xi##D = a3i*w3r + a3r*w3i; }

// inverse radix-4 fused (two DIT levels M/2, M), conjugate twiddles.
#define BTF4I(A,B,C,D) { \
    const float m1r = xr##B*w3r - xi##B*w3i, m1i = xi##B*w3r + xr##B*w3i; \
    const float s0r = xr##A + m1r, s0i = xi##A + m1i; \
    const float s1r = xr##A - m1r, s1i = xi##A - m1i; \
    const float m3r = xr##D*w3r - xi##D*w3i, m3i = xi##D*w3r + xr##D*w3i; \
    const float s2r = xr##C + m3r, s2i = xi##C + m3i; \
    const float s3r = xr##C - m3r, s3i = xi##C - m3i; \
    const float t2r = s2r*w1r - s2i*w1i, t2i = s2i*w1r + s2r*w1i; \
    const float n3r = s3r*w1r - s3i*w1i, n3i = s3i*w1r + s3r*w1i; \
    const float t3r = -n3i, t3i = n3r; \
    xr##A = s0r + t2r; xi##A = s0i + t2i; \
    xr##C = s0r - t2r; xi##C = s0i - t2i; \
    xr##B = s1r + t3r; xi##B = s1i + t3i; \
    xr##D = s1r - t3r; xi##D = s1i - t3i; }

// ---- head6: levels 1024,512,256,128 (LDS-held scalars) + 64,32 (permlane).
// Lane owns {lane + 64j}; ONE LDS round trip for SIX levels.
__device__ __forceinline__ void head6_fwd(float* __restrict__ pr, float* __restrict__ pi,
                                          const float* __restrict__ tab, int lane)
{
    const int A0 = 36 * (lane >> 5) + (lane & 31);
    const float tc = tab[TPHYS(lane)];
    const float ts = tab[544 + TPHYS(lane)];
    const float wbr = tc, wbi = -ts;                     // W^lane (forward)
    const float w2r = wbr*wbr - wbi*wbi, w2i = 2.f*wbr*wbi;
    const float w4r = w2r*w2r - w2i*w2i, w4i = 2.f*w2r*w2i;
    const float w8r = w4r*w4r - w4i*w4i, w8i = 2.f*w4r*w4i;
    const int e64 = (lane & 31) << 4;
    const float c64 = tab[TPHYS(e64)], s64 = tab[544 + TPHYS(e64)];
    const float w64r = c64, w64i = -s64;                 // W_64^{lane&31}
    const int e32 = (lane & 15) << 5;
    const float c32 = tab[TPHYS(e32)], s32 = tab[544 + TPHYS(e32)];
    const float w32r = c32, w32i = -s32;                 // W_32^{lane&15}
    const bool up32 = (lane & 32) != 0;
    const bool up16 = (lane & 16) != 0;
#define HD(J) float xr##J = pr[A0 + 72*J]; float xi##J = pi[A0 + 72*J];
    HD(0) HD(1) HD(2) HD(3) HD(4) HD(5) HD(6) HD(7)
    HD(8) HD(9) HD(10) HD(11) HD(12) HD(13) HD(14) HD(15)
#undef HD
    // stage A: M=1024 (levels 1024,512); groups (j, j+4, j+8, j+12)
#define STA(JA,JB,JC,JD,J16) { \
    const float w1r = wbr*K16C[J16] + wbi*K16S[J16]; \
    const float w1i = wbi*K16C[J16] - wbr*K16S[J16]; \
    const float w3r = w1r*w1r - w1i*w1i, w3i = 2.f*w1r*w1i; \
    BTF4F(JA,JB,JC,JD) }
    STA(0,4,8,12,0) STA(1,5,9,13,1) STA(2,6,10,14,2) STA(3,7,11,15,3)
#undef STA
    // stage B: M=256 (levels 256,128); groups (4g..4g+3)
    {
        const float w1r = w4r, w1i = w4i, w3r = w8r, w3i = w8i;
        BTF4F(0,1,2,3) BTF4F(4,5,6,7) BTF4F(8,9,10,11) BTF4F(12,13,14,15)
    }
    // stage C1: level 64 (distance 32) via permlane32_swap (VALU)
#define L64F(J) { \
    float lr_, hr_, li_, hi_; \
    swap32(xr##J, lr_, hr_); swap32(xi##J, li_, hi_); \
    const float sr = lr_ + hr_, si = li_ + hi_; \
    const float dr = lr_ - hr_, di = li_ - hi_; \
    const float mr = dr*w64r - di*w64i, mi = di*w64r + dr*w64i; \
    xr##J = up32 ? mr : sr;  xi##J = up32 ? mi : si; }
    L64F(0) L64F(1) L64F(2) L64F(3) L64F(4) L64F(5) L64F(6) L64F(7)
    L64F(8) L64F(9) L64F(10) L64F(11) L64F(12) L64F(13) L64F(14) L64F(15)
#undef L64F
    // stage C2: level 32 (distance 16) via permlane16_swap
#define L32F(J) { \
    float lr_, hr_, li_, hi_; \
    swap16(xr##J, lr_, hr_); swap16(xi##J, li_, hi_); \
    const float sr = lr_ + hr_, si = li_ + hi_; \
    const float dr = lr_ - hr_, di = li_ - hi_; \
    const float mr = dr*w32r - di*w32i, mi = di*w32r + dr*w32i; \
    xr##J = up16 ? mr : sr;  xi##J = up16 ? mi : si; }
    L32F(0) L32F(1) L32F(2) L32F(3) L32F(4) L32F(5) L32F(6) L32F(7)
    L32F(8) L32F(9) L32F(10) L32F(11) L32F(12) L32F(13) L32F(14) L32F(15)
#undef L32F
#define HS(J) pr[A0 + 72*J] = xr##J; pi[A0 + 72*J] = xi##J;
    HS(0) HS(1) HS(2) HS(3) HS(4) HS(5) HS(6) HS(7)
    HS(8) HS(9) HS(10) HS(11) HS(12) HS(13) HS(14) HS(15)
#undef HS
}

// inverse head6: levels 32, 64 (permlane, conj), then 128,256 and 512,1024.
__device__ __forceinline__ void head6_inv(float* __restrict__ pr, float* __restrict__ pi,
                                          const float* __restrict__ tab, int lane)
{
    const int A0 = 36 * (lane >> 5) + (lane & 31);
    const float tc = tab[TPHYS(lane)];
    const float ts = tab[544 + TPHYS(lane)];
    const float vbr = tc, vbi = ts;                      // conj(W^lane)
    const float v2r = vbr*vbr - vbi*vbi, v2i = 2.f*vbr*vbi;
    const float v4r = v2r*v2r - v2i*v2i, v4i = 2.f*v2r*v2i;
    const float v8r = v4r*v4r - v4i*v4i, v8i = 2.f*v4r*v4i;
    const int e64 = (lane & 31) << 4;
    const float c64 = tab[TPHYS(e64)], s64 = tab[544 + TPHYS(e64)];
    const float v64r = c64, v64i = s64;
    const int e32 = (lane & 15) << 5;
    const float c32 = tab[TPHYS(e32)], s32 = tab[544 + TPHYS(e32)];
    const float v32r = c32, v32i = s32;
    const bool up32 = (lane & 32) != 0;
    const bool up16 = (lane & 16) != 0;
#define HD(J) float xr##J = pr[A0 + 72*J]; float xi##J = pi[A0 + 72*J];
    HD(0) HD(1) HD(2) HD(3) HD(4) HD(5) HD(6) HD(7)
    HD(8) HD(9) HD(10) HD(11) HD(12) HD(13) HD(14) HD(15)
#undef HD
    // level 32 (DIT): b' = hi * conj(w); low = lo+b', high = lo-b'
#define L32I(J) { \
    float lr_, hr_, li_, hi_; \
    swap16(xr##J, lr_, hr_); swap16(xi##J, li_, hi_); \
    const float mr = hr_*v32r - hi_*v32i, mi = hi_*v32r + hr_*v32i; \
    xr##J = up16 ? (lr_ - mr) : (lr_ + mr); \
    xi##J = up16 ? (li_ - mi) : (li_ + mi); }
    L32I(0) L32I(1) L32I(2) L32I(3) L32I(4) L32I(5) L32I(6) L32I(7)
    L32I(8) L32I(9) L32I(10) L32I(11) L32I(12) L32I(13) L32I(14) L32I(15)
#undef L32I
    // level 64 (DIT)
#define L64I(J) { \
    float lr_, hr_, li_, hi_; \
    swap32(xr##J, lr_, hr_); swap32(xi##J, li_, hi_); \
    const float mr = hr_*v64r - hi_*v64i, mi = hi_*v64r + hr_*v64i; \
    xr##J = up32 ? (lr_ - mr) : (lr_ + mr); \
    xi##J = up32 ? (li_ - mi) : (li_ + mi); }
    L64I(0) L64I(1) L64I(2) L64I(3) L64I(4) L64I(5) L64I(6) L64I(7)
    L64I(8) L64I(9) L64I(10) L64I(11) L64I(12) L64I(13) L64I(14) L64I(15)
#undef L64I
    {   // M=256 (levels 128,256)
        const float w1r = v4r, w1i = v4i, w3r = v8r, w3i = v8i;
        BTF4I(0,1,2,3) BTF4I(4,5,6,7) BTF4I(8,9,10,11) BTF4I(12,13,14,15)
    }
    // M=1024 (levels 512,1024)
#define STB(JA,JB,JC,JD,J16) { \
    const float w1r = vbr*K16C[J16] - vbi*K16S[J16]; \
    const float w1i = vbi*K16C[J16] + vbr*K16S[J16]; \
    const float w3r = w1r*w1r - w1i*w1i, w3i = 2.f*w1r*w1i; \
    BTF4I(JA,JB,JC,JD) }
    STB(0,4,8,12,0) STB(1,5,9,13,1) STB(2,6,10,14,2) STB(3,7,11,15,3)
#undef STB
#define HS(J) pr[A0 + 72*J] = xr##J; pi[A0 + 72*J] = xi##J;
    HS(0) HS(1) HS(2) HS(3) HS(4) HS(5) HS(6) HS(7)
    HS(8) HS(9) HS(10) HS(11) HS(12) HS(13) HS(14) HS(15)
#undef HS
}

// ---- tail4: levels 16,8,4,2 in ONE pass on the lane's contiguous 16-block.
__device__ __forceinline__ void tail4_fwd(float* __restrict__ pr, float* __restrict__ pi, int lane)
{
    const int Pb = PHYS(lane << 4);
    float4 r0 = *(const float4*)(pr + Pb),      r1 = *(const float4*)(pr + Pb + 4);
    float4 r2 = *(const float4*)(pr + Pb + 8),  r3 = *(const float4*)(pr + Pb + 12);
    float4 i0 = *(const float4*)(pi + Pb),      i1 = *(const float4*)(pi + Pb + 4);
    float4 i2 = *(const float4*)(pi + Pb + 8),  i3 = *(const float4*)(pi + Pb + 12);
#define TCF(CMP, C) { \
    const float w1r = K16C[C], w1i = -K16S[C]; \
    const float w3r = w1r*w1r - w1i*w1i, w3i = 2.f*w1r*w1i; \
    const float t0r = r0.CMP + r2.CMP, t0i = i0.CMP + i2.CMP; \
    const float d2r = r0.CMP - r2.CMP, d2i = i0.CMP - i2.CMP; \
    const float t2r = d2r*w1r - d2i*w1i, t2i = d2i*w1r + d2r*w1i; \
    const float t1r = r1.CMP + r3.CMP, t1i = i1.CMP + i3.CMP; \
    const float d3r = r1.CMP - r3.CMP, d3i = i1.CMP - i3.CMP; \
    const float m3r = d3r*w1r - d3i*w1i, m3i = d3i*w1r + d3r*w1i; \
    const float t3r = m3i, t3i = -m3r; \
    const float a0r = t0r+t1r, a0i = t0i+t1i; \
    const float a1r = t0r-t1r, a1i = t0i-t1i; \
    const float a2r = t2r+t3r, a2i = t2i+t3i; \
    const float a3r = t2r-t3r, a3i = t2i-t3i; \
    r0.CMP = a0r; i0.CMP = a0i; \
    r1.CMP = a1r*w3r - a1i*w3i; i1.CMP = a1i*w3r + a1r*w3i; \
    r2.CMP = a2r; i2.CMP = a2i; \
    r3.CMP = a3r*w3r - a3i*w3i; i3.CMP = a3i*w3r + a3r*w3i; }
    TCF(x,0) TCF(y,1) TCF(z,2) TCF(w,3)
#undef TCF
#define Q4F(RQ, IQ) { \
    const float t0r = RQ.x + RQ.z, t0i = IQ.x + IQ.z; \
    const float t2r = RQ.x - RQ.z, t2i = IQ.x - IQ.z; \
    const float t1r = RQ.y + RQ.w, t1i = IQ.y + IQ.w; \
    const float d3r = RQ.y - RQ.w, d3i = IQ.y - IQ.w; \
    const float t3r = d3i, t3i = -d3r; \
    RQ.x = t0r + t1r; IQ.x = t0i + t1i; \
    RQ.y = t0r - t1r; IQ.y = t0i - t1i; \
    RQ.z = t2r + t3r; IQ.z = t2i + t3i; \
    RQ.w = t2r - t3r; IQ.w = t2i - t3i; }
    Q4F(r0, i0) Q4F(r1, i1) Q4F(r2, i2) Q4F(r3, i3)
#undef Q4F
    *(float4*)(pr + Pb) = r0;      *(float4*)(pr + Pb + 4) = r1;
    *(float4*)(pr + Pb + 8) = r2;  *(float4*)(pr + Pb + 12) = r3;
    *(float4*)(pi + Pb) = i0;      *(float4*)(pi + Pb + 4) = i1;
    *(float4*)(pi + Pb + 8) = i2;  *(float4*)(pi + Pb + 12) = i3;
}

__device__ __forceinline__ void tail4_inv(float* __restrict__ pr, float* __restrict__ pi, int lane)
{
    const int Pb = PHYS(lane << 4);
    float4 r0 = *(const float4*)(pr + Pb),      r1 = *(const float4*)(pr + Pb + 4);
    float4 r2 = *(const float4*)(pr + Pb + 8),  r3 = *(const float4*)(pr + Pb + 12);
    float4 i0 = *(const float4*)(pi + Pb),      i1 = *(const float4*)(pi + Pb + 4);
    float4 i2 = *(const float4*)(pi + Pb + 8),  i3 = *(const float4*)(pi + Pb + 12);
#define Q4I(RQ, IQ) { \
    const float s0r = RQ.x + RQ.y, s0i = IQ.x + IQ.y; \
    const float s1r = RQ.x - RQ.y, s1i = IQ.x - IQ.y; \
    const float s2r = RQ.z + RQ.w, s2i = IQ.z + IQ.w; \
    const float s3r = RQ.z - RQ.w, s3i = IQ.z - IQ.w; \
    const float p3r = -s3i, p3i = s3r; \
    RQ.x = s0r + s2r; IQ.x = s0i + s2i; \
    RQ.z = s0r - s2r; IQ.z = s0i - s2i; \
    RQ.y = s1r + p3r; IQ.y = s1i + p3i; \
    RQ.w = s1r - p3r; IQ.w = s1i - p3i; }
    Q4I(r0, i0) Q4I(r1, i1) Q4I(r2, i2) Q4I(r3, i3)
#undef Q4I
#define TCI(CMP, C) { \
    const float w1r = K16C[C], w1i = K16S[C]; \
    const float w3r = w1r*w1r - w1i*w1i, w3i = 2.f*w1r*w1i; \
    const float m1r = r1.CMP*w3r - i1.CMP*w3i, m1i = i1.CMP*w3r + r1.CMP*w3i; \
    const float s0r = r0.CMP + m1r, s0i = i0.CMP + m1i; \
    const float s1r = r0.CMP - m1r, s1i = i0.CMP - m1i; \
    const float m3r = r3.CMP*w3r - i3.CMP*w3i, m3i = i3.CMP*w3r + r3.CMP*w3i; \
    const float s2r = r2.CMP + m3r, s2i = i2.CMP + m3i; \
    const float s3r = r2.CMP - m3r, s3i = i2.CMP - m3i; \
    const float t2r = s2r*w1r - s2i*w1i, t2i = s2i*w1r + s2r*w1i; \
    const float n3r = s3r*w1r - s3i*w1i, n3i = s3i*w1r + s3r*w1i; \
    const float t3r = -n3i, t3i = n3r; \
    r0.CMP = s0r + t2r; i0.CMP = s0i + t2i; \
    r2.CMP = s0r - t2r; i2.CMP = s0i - t2i; \
    r1.CMP = s1r + t3r; i1.CMP = s1i + t3i; \
    r3.CMP = s1r - t3r; i3.CMP = s1i - t3i; }
    TCI(x,0) TCI(y,1) TCI(z,2) TCI(w,3)
#undef TCI
    *(float4*)(pr + Pb) = r0;      *(float4*)(pr + Pb + 4) = r1;
    *(float4*)(pr + Pb + 8) = r2;  *(float4*)(pr + Pb + 12) = r3;
    *(float4*)(pi + Pb) = i0;      *(float4*)(pi + Pb + 4) = i1;
    *(float4*)(pi + Pb + 8) = i2;  *(float4*)(pi + Pb + 12) = i3;
}

// ---------------- Kernel A: FFT autocorrelation (LDS-resident) ----------------
// grid (NE/8, NH, NB), block 512 = 8 waves; 8 series/block, one per wave.
__global__ __launch_bounds__(512) void fftcorr_kernel(
    const float* __restrict__ q, const float* __restrict__ k,
    float* __restrict__ corr_out, float* __restrict__ ws_mean)
{
    extern __shared__ float LDSF[];
    const int tid = threadIdx.x;
    const int n = blockIdx.z, h = blockIdx.y, e0 = blockIdx.x * 8;

    // twiddle table: (cos,sin)(2*pi*t/1024), t = 0..511
    {
        float sv, cv;
        __sincosf((float)tid * (6.2831853071795865f / 1024.f), &sv, &cv);
        LDSF[TBO + TPHYS(tid)] = cv;
        LDSF[TBO + 544 + TPHYS(tid)] = sv;
    }

    // stage: z.re-plane = q, z.im-plane = k (float4 global loads; 4096 total)
    {
#pragma unroll
        for (int c = 0; c < 8; ++c) {
            const int idx = c * 512 + tid;
            const int isk = idx >> 11;
            const int rem = idx & 2047;
            const int t  = rem >> 1;
            const int eh = rem & 1;
            const float* __restrict__ src = isk ? k : q;
            const size_t g = ((((size_t)n * L_SEQ + t) * NH + h) * NE) + e0 + 4 * eh;
            const float4 v = *reinterpret_cast<const float4*>(src + g);
            const int ph = PHYS(t);
            LDSF[(size_t)(2 * (4 * eh + 0) + isk) * PS + ph] = v.x;
            LDSF[(size_t)(2 * (4 * eh + 1) + isk) * PS + ph] = v.y;
            LDSF[(size_t)(2 * (4 * eh + 2) + isk) * PS + ph] = v.z;
            LDSF[(size_t)(2 * (4 * eh + 3) + isk) * PS + ph] = v.w;
        }
    }
    __syncthreads();

    const int w = tid >> 6;
    const int lane = tid & 63;
    const float* tab = LDSF + TBO;

    {
        float* pr = LDSF + (size_t)(2 * w) * PS;
        float* pi = pr + PS;

        // forward DIF: 2 LDS passes (1024..32 | 16,8,4,2)
        head6_fwd(pr, pi, tab, lane);
        tail4_fwd(pr, pi, lane);

        // unpack v3: S = Q*conj(K)/1024 from z(p), z(pb), exact conj pairs.
        const int Pb = PHYS(lane << 4);
        float4 s0r, s0i, s1r, s1i, s2r, s2i, s3r, s3i;
#define UQ(QI) { \
        const float4 a_r = *(const float4*)(pr + Pb + 4*QI); \
        const float4 a_i = *(const float4*)(pi + Pb + 4*QI); \
        UNPC(QI, x, 0) UNPC(QI, y, 1) UNPC(QI, z, 2) UNPC(QI, w, 3) }
#define UNPC(QI, CMP, JJ) { \
        const int p  = (lane << 4) + 4*QI + JJ; \
        const int f  = (int)(__brev((unsigned)p) >> 22); \
        const int fb = (1024 - f) & 1023; \
        const int pb = (int)(__brev((unsigned)fb) >> 22); \
        const int Ppb = PHYS(pb); \
        const float brv = pr[Ppb], biv = pi[Ppb]; \
        const float arv = a_r.CMP, aiv = a_i.CMP; \
        const float Qr = 0.5f*(arv + brv), Qi = 0.5f*(aiv - biv); \
        const float Kr = 0.5f*(aiv + biv), Ki = 0.5f*(brv - arv); \
        s##QI##r.CMP = (Qr*Kr + Qi*Ki) * (1.f/1024.f); \
        s##QI##i.CMP = (Qi*Kr - Qr*Ki) * (1.f/1024.f); }
        UQ(0) UQ(1) UQ(2) UQ(3)
#undef UNPC
#undef UQ
        *(float4*)(pr + Pb)      = s0r;  *(float4*)(pi + Pb)      = s0i;
        *(float4*)(pr + Pb + 4)  = s1r;  *(float4*)(pi + Pb + 4)  = s1i;
        *(float4*)(pr + Pb + 8)  = s2r;  *(float4*)(pi + Pb + 8)  = s2i;
        *(float4*)(pr + Pb + 12) = s3r;  *(float4*)(pi + Pb + 12) = s3i;

        // inverse DIT: 2 LDS passes (2..16 | 32..1024)
        tail4_inv(pr, pi, lane);
        head6_inv(pr, pi, tab, lane);
    }
    __syncthreads();

    // writeout: per-lane float4 across 4 re-planes + 32B global write + mean
    {
#pragma unroll
        for (int c = 0; c < 4; ++c) {
            const int f4idx = c * 512 + tid;
            const int l  = f4idx >> 1;
            const int j4 = f4idx & 1;
            const int ph = PHYS(l);
            float4 v;
            v.x = LDSF[(size_t)(2 * (4 * j4 + 0)) * PS + ph];
            v.y = LDSF[(size_t)(2 * (4 * j4 + 1)) * PS + ph];
            v.z = LDSF[(size_t)(2 * (4 * j4 + 2)) * PS + ph];
            v.w = LDSF[(size_t)(2 * (4 * j4 + 3)) * PS + ph];
            *reinterpret_cast<float4*>(
                corr_out + ((((size_t)n * L_SEQ + l) * NH + h) * NE) + e0 + 4 * j4) = v;
            const float esum = v.x + v.y + v.z + v.w;
            const float tot = esum + __shfl_xor(esum, 1, 64);
            if ((tid & 1) == 0) atomicAdd(&ws_mean[n * L_SEQ + l], tot);
        }
    }
}

// ---------------- Kernel B: top-6 lags + per-n softmax ----------------
__global__ __launch_bounds__(1024) void topk_softmax_kernel(
    const float* __restrict__ ws_mean, int* __restrict__ ws_idx,
    float* __restrict__ ws_w)
{
    __shared__ float val[1024];
    __shared__ float rv[1024];
    __shared__ int   ri[1024];
    __shared__ int   sel[TOPK];
    const int tid = threadIdx.x;

    float s = 0.f;
    for (int n = 0; n < NB; ++n) s += ws_mean[n * L_SEQ + tid];
    val[tid] = s;
    __syncthreads();

    for (int kk = 0; kk < TOPK; ++kk) {
        rv[tid] = val[tid];
        ri[tid] = tid;
        __syncthreads();
        for (int off = 512; off > 0; off >>= 1) {
            if (tid < off) {
                const float a = rv[tid], b = rv[tid + off];
                const int ia = ri[tid], ib = ri[tid + off];
                if (b > a || (b == a && ib < ia)) { rv[tid] = b; ri[tid] = ib; }
            }
            __syncthreads();
        }
        if (tid == 0) { sel[kk] = ri[0]; val[ri[0]] = -1e30f; }
        __syncthreads();
    }
    if (tid < TOPK) ws_idx[tid] = sel[tid];

    if (tid < NB) {
        float wv[TOPK];
        float m = -1e30f;
        for (int kk = 0; kk < TOPK; ++kk) {
            wv[kk] = ws_mean[tid * L_SEQ + sel[kk]] * (1.f / (NH * NE));
            m = fmaxf(m, wv[kk]);
        }
        float sum = 0.f;
        for (int kk = 0; kk < TOPK; ++kk) { wv[kk] = expf(wv[kk] - m); sum += wv[kk]; }
        const float inv = 1.f / sum;
        for (int kk = 0; kk < TOPK; ++kk) ws_w[tid * 8 + kk] = wv[kk] * inv;
    }
}

// ---------------- Kernel C: lag-gather weighted sum of v ----------------
__global__ __launch_bounds__(256) void gather_kernel(
    const float* __restrict__ v, const int* __restrict__ ws_idx,
    const float* __restrict__ ws_w, float* __restrict__ out)
{
    const int n = blockIdx.y;
    const int idx4 = blockIdx.x * 256 + threadIdx.x;
    const int l = idx4 >> 7;
    const int r = idx4 & 127;
    const float* wrow = ws_w + n * 8;

    float4 acc = make_float4(0.f, 0.f, 0.f, 0.f);
#pragma unroll
    for (int kk = 0; kk < TOPK; ++kk) {
        const int t = (l + ws_idx[kk]) & (L_SEQ - 1);
        const float4 vv = *reinterpret_cast<const float4*>(
            v + (((size_t)n * L_SEQ + t) * (NH * NE)) + r * 4);
        const float wk = wrow[kk];
        acc.x = fmaf(wk, vv.x, acc.x);
        acc.y = fmaf(wk, vv.y, acc.y);
        acc.z = fmaf(wk, vv.z, acc.z);
        acc.w = fmaf(wk, vv.w, acc.w);
    }
    *reinterpret_cast<float4*>(out + ((size_t)n * L_SEQ + l) * (NH * NE) + r * 4) = acc;
}

extern "C" void kernel_launch(void* const* d_in, const int* in_sizes, int n_in,
                              void* d_out, int out_size, void* d_ws, size_t ws_size,
                              hipStream_t stream)
{
    const float* q = (const float*)d_in[0];
    const float* k = (const float*)d_in[1];
    const float* v = (const float*)d_in[2];
    float* out = (float*)d_out;
    float* corr_out = out + (size_t)NB * L_SEQ * NH * NE;

    float* ws_mean = (float*)d_ws;                              // 32*1024 f32
    int*   ws_idx  = (int*)((char*)d_ws + 131072);              // 6 ints
    float* ws_w    = (float*)((char*)d_ws + 131072 + 256);      // 32*8 f32

    hipMemsetAsync(d_ws, 0, 131072, stream);
    const size_t lds_bytes = (size_t)LDS_FLOATS * sizeof(float);   // 78,080 B
    fftcorr_kernel<<<dim3(NE / 8, NH, NB), 512, lds_bytes, stream>>>(q, k, corr_out, ws_mean);
    topk_softmax_kernel<<<1, 1024, 0, stream>>>(ws_mean, ws_idx, ws_w);
    gather_kernel<<<dim3(512, NB), 256, 0, stream>>>(v, ws_idx, ws_w, out);
}

// Round 13
// 189.605 us; speedup vs baseline: 1.0058x; 1.0058x over previous
//
#include <hip/hip_runtime.h>

#define L_SEQ 1024
#define NB 32
#define NH 8
#define NE 64
#define TOPK 6

// LDS geometry: 16 data planes (8 series x {re,im}) + twiddle table.
// Plane: 1024 floats stored as 32 groups of 32 at stride 36 (12.5% pad).
// 16*1152*4B + table = 75,904 B -> 2 blocks/CU (verified round 9/10: occ ~36%).
#define PS   1152
#define TBO  (16 * PS)            // table offset: TC[272] then TS[272]
#define PHYS(L)  (36 * ((L) >> 5) + ((L) & 31))
#define TPHYS(E) ((E) + ((E) >> 4))
#define LDS_FLOATS (TBO + 544)    // 18,976 floats = 75,904 B

// W16^j = (cos(pi j/8), sin(pi j/8)), j = 0..3 (compile-time twiddle steps)
constexpr float K16C[4] = {1.f, 0.92387953f, 0.70710678f, 0.38268343f};
constexpr float K16S[4] = {0.f, 0.38268343f, 0.70710678f, 0.92387953f};

// ---------------------------------------------------------------------------
// Register discipline (rounds 2-7): named scalars / named float4 ONLY.
// Round-12 lesson: relocating exchange work LDS->VALU at equal op count is a
// net loss (151->160); this round REMOVES round-trips via tail fusion instead.
// ---------------------------------------------------------------------------

// radix-4 fused butterfly (two DIF levels M, M/2) on named scalars xr#/xi#.
#define BTF4F(A,B,C,D) { \
    const float t0r = xr##A + xr##C, t0i = xi##A + xi##C; \
    const float d2r = xr##A - xr##C, d2i = xi##A - xi##C; \
    const float t2r = d2r*w1r - d2i*w1i, t2i = d2i*w1r + d2r*w1i; \
    const float t1r = xr##B + xr##D, t1i = xi##B + xi##D; \
    const float d3r = xr##B - xr##D, d3i = xi##B - xi##D; \
    const float m3r = d3r*w1r - d3i*w1i, m3i = d3i*w1r + d3r*w1i; \
    const float t3r = m3i, t3i = -m3r; \
    const float a0r = t0r + t1r, a0i = t0i + t1i; \
    const float a1r = t0r - t1r, a1i = t0i - t1i; \
    const float a2r = t2r + t3r, a2i = t2i + t3i; \
    const float a3r = t2r - t3r, a3i = t2i - t3i; \
    xr##A = a0r; xi##A = a0i; \
    xr##B = a1r*w3r - a1i*w3i; xi##B = a1i*w3r + a1r*w3i; \
    xr##C = a2r; xi##C = a2i; \
    xr##D = a3r*w3r - a3i*w3i; xi##D = a3i*w3r + a3r*w3i; }

// inverse radix-4 fused (two DIT levels M/2, M), conjugate twiddles.
#define BTF4I(A,B,C,D) { \
    const float m1r = xr##B*w3r - xi##B*w3i, m1i = xi##B*w3r + xr##B*w3i; \
    const float s0r = xr##A + m1r, s0i = xi##A + m1i; \
    const float s1r = xr##A - m1r, s1i = xi##A - m1i; \
    const float m3r = xr##D*w3r - xi##D*w3i, m3i = xi##D*w3r + xr##D*w3i; \
    const float s2r = xr##C + m3r, s2i = xi##C + m3i; \
    const float s3r = xr##C - m3r, s3i = xi##C - m3i; \
    const float t2r = s2r*w1r - s2i*w1i, t2i = s2i*w1r + s2r*w1i; \
    const float n3r = s3r*w1r - s3i*w1i, n3i = s3i*w1r + s3r*w1i; \
    const float t3r = -n3i, t3i = n3r; \
    xr##A = s0r + t2r; xi##A = s0i + t2i; \
    xr##C = s0r - t2r; xi##C = s0i - t2i; \
    xr##B = s1r + t3r; xi##B = s1i + t3i; \
    xr##D = s1r - t3r; xi##D = s1i - t3i; }

// ---- head4: levels 1024,512,256,128 in ONE pass. Lane owns {lane + 64j}.
// PHYS(lane+64j) = A0 + 72j; every scalar op = 2 lanes/bank (free, verified).
__device__ __forceinline__ void head4_fwd(float* __restrict__ pr, float* __restrict__ pi,
                                          const float* __restrict__ tab, int lane)
{
    const int A0 = 36 * (lane >> 5) + (lane & 31);
    const float tc = tab[TPHYS(lane)];
    const float ts = tab[272 + TPHYS(lane)];
    const float wbr = tc, wbi = -ts;                     // W^lane (forward)
    const float w2r = wbr*wbr - wbi*wbi, w2i = 2.f*wbr*wbi;
    const float w4r = w2r*w2r - w2i*w2i, w4i = 2.f*w2r*w2i;
    const float w8r = w4r*w4r - w4i*w4i, w8i = 2.f*w4r*w4i;
#define HD(J) float xr##J = pr[A0 + 72*J]; float xi##J = pi[A0 + 72*J];
    HD(0) HD(1) HD(2) HD(3) HD(4) HD(5) HD(6) HD(7)
    HD(8) HD(9) HD(10) HD(11) HD(12) HD(13) HD(14) HD(15)
#undef HD
    // stage A: M=1024 (levels 1024,512); groups (j, j+4, j+8, j+12)
#define STA(JA,JB,JC,JD,J16) { \
    const float w1r = wbr*K16C[J16] + wbi*K16S[J16]; \
    const float w1i = wbi*K16C[J16] - wbr*K16S[J16]; \
    const float w3r = w1r*w1r - w1i*w1i, w3i = 2.f*w1r*w1i; \
    BTF4F(JA,JB,JC,JD) }
    STA(0,4,8,12,0) STA(1,5,9,13,1) STA(2,6,10,14,2) STA(3,7,11,15,3)
#undef STA
    // stage B: M=256 (levels 256,128); groups (4g..4g+3); u0 = lane -> w1 = wb^4
    {
        const float w1r = w4r, w1i = w4i, w3r = w8r, w3i = w8i;
        BTF4F(0,1,2,3) BTF4F(4,5,6,7) BTF4F(8,9,10,11) BTF4F(12,13,14,15)
    }
#define HS(J) pr[A0 + 72*J] = xr##J; pi[A0 + 72*J] = xi##J;
    HS(0) HS(1) HS(2) HS(3) HS(4) HS(5) HS(6) HS(7)
    HS(8) HS(9) HS(10) HS(11) HS(12) HS(13) HS(14) HS(15)
#undef HS
}

// inverse head4: levels 128,256 then 512,1024 (conjugate twiddles)
__device__ __forceinline__ void head4_inv(float* __restrict__ pr, float* __restrict__ pi,
                                          const float* __restrict__ tab, int lane)
{
    const int A0 = 36 * (lane >> 5) + (lane & 31);
    const float tc = tab[TPHYS(lane)];
    const float ts = tab[272 + TPHYS(lane)];
    const float vbr = tc, vbi = ts;                      // conj(W^lane)
    const float v2r = vbr*vbr - vbi*vbi, v2i = 2.f*vbr*vbi;
    const float v4r = v2r*v2r - v2i*v2i, v4i = 2.f*v2r*v2i;
    const float v8r = v4r*v4r - v4i*v4i, v8i = 2.f*v4r*v4i;
#define HD(J) float xr##J = pr[A0 + 72*J]; float xi##J = pi[A0 + 72*J];
    HD(0) HD(1) HD(2) HD(3) HD(4) HD(5) HD(6) HD(7)
    HD(8) HD(9) HD(10) HD(11) HD(12) HD(13) HD(14) HD(15)
#undef HD
    {   // stage 1: M=256 (levels 128,256)
        const float w1r = v4r, w1i = v4i, w3r = v8r, w3i = v8i;
        BTF4I(0,1,2,3) BTF4I(4,5,6,7) BTF4I(8,9,10,11) BTF4I(12,13,14,15)
    }
    // stage 2: M=1024 (levels 512,1024)
#define STB(JA,JB,JC,JD,J16) { \
    const float w1r = vbr*K16C[J16] - vbi*K16S[J16]; \
    const float w1i = vbi*K16C[J16] + vbr*K16S[J16]; \
    const float w3r = w1r*w1r - w1i*w1i, w3i = 2.f*w1r*w1i; \
    BTF4I(JA,JB,JC,JD) }
    STB(0,4,8,12,0) STB(1,5,9,13,1) STB(2,6,10,14,2) STB(3,7,11,15,3)
#undef STB
#define HS(J) pr[A0 + 72*J] = xr##J; pi[A0 + 72*J] = xi##J;
    HS(0) HS(1) HS(2) HS(3) HS(4) HS(5) HS(6) HS(7)
    HS(8) HS(9) HS(10) HS(11) HS(12) HS(13) HS(14) HS(15)
#undef HS
}

// ---- mid stage (levels 64,32): verified round-9/10 code (LG=4)
template<int LG>
__device__ __forceinline__ void dif_dstage(float* __restrict__ pr, float* __restrict__ pi,
                                           const float* __restrict__ tab, int lane)
{
    const int b0 = lane << 2;
    const int u0 = b0 & ((1 << LG) - 1);
    const int Lb = ((b0 >> LG) << (LG + 2)) + u0;
    const int P0 = PHYS(Lb);
    const int P1 = PHYS(Lb + (1 << LG));
    const int P2 = PHYS(Lb + (2 << LG));
    const int P3 = PHYS(Lb + (3 << LG));
    float4 r0 = *(const float4*)(pr + P0), r1 = *(const float4*)(pr + P1);
    float4 r2 = *(const float4*)(pr + P2), r3 = *(const float4*)(pr + P3);
    float4 i0 = *(const float4*)(pi + P0), i1 = *(const float4*)(pi + P1);
    float4 i2 = *(const float4*)(pi + P2), i3 = *(const float4*)(pi + P3);
#define CBTF(CMP, II) { \
    const int e1 = (u0 + II) << (8 - LG); \
    const float w1c = tab[TPHYS(e1)]; \
    const float w1s = tab[272 + TPHYS(e1)]; \
    const float w3c = w1c * w1c - w1s * w1s; \
    const float w3s = 2.f * w1c * w1s; \
    const float t0r = r0.CMP + r2.CMP, t0i = i0.CMP + i2.CMP; \
    const float d2r = r0.CMP - r2.CMP, d2i = i0.CMP - i2.CMP; \
    const float t2r = d2r * w1c + d2i * w1s, t2i = d2i * w1c - d2r * w1s; \
    const float t1r = r1.CMP + r3.CMP, t1i = i1.CMP + i3.CMP; \
    const float d3r = r1.CMP - r3.CMP, d3i = i1.CMP - i3.CMP; \
    const float m3r = d3r * w1c + d3i * w1s, m3i = d3i * w1c - d3r * w1s; \
    const float t3r = m3i, t3i = -m3r; \
    const float a0r = t0r + t1r, a0i = t0i + t1i; \
    const float a1r = t0r - t1r, a1i = t0i - t1i; \
    const float a2r = t2r + t3r, a2i = t2i + t3i; \
    const float a3r = t2r - t3r, a3i = t2i - t3i; \
    r0.CMP = a0r;                     i0.CMP = a0i; \
    r1.CMP = a1r * w3c + a1i * w3s;   i1.CMP = a1i * w3c - a1r * w3s; \
    r2.CMP = a2r;                     i2.CMP = a2i; \
    r3.CMP = a3r * w3c + a3i * w3s;   i3.CMP = a3i * w3c - a3r * w3s; }
    CBTF(x, 0) CBTF(y, 1) CBTF(z, 2) CBTF(w, 3)
#undef CBTF
    *(float4*)(pr + P0) = r0; *(float4*)(pr + P1) = r1;
    *(float4*)(pr + P2) = r2; *(float4*)(pr + P3) = r3;
    *(float4*)(pi + P0) = i0; *(float4*)(pi + P1) = i1;
    *(float4*)(pi + P2) = i2; *(float4*)(pi + P3) = i3;
}

template<int LG>
__device__ __forceinline__ void dit_dstage(float* __restrict__ pr, float* __restrict__ pi,
                                           const float* __restrict__ tab, int lane)
{
    const int b0 = lane << 2;
    const int u0 = b0 & ((1 << LG) - 1);
    const int Lb = ((b0 >> LG) << (LG + 2)) + u0;
    const int P0 = PHYS(Lb);
    const int P1 = PHYS(Lb + (1 << LG));
    const int P2 = PHYS(Lb + (2 << LG));
    const int P3 = PHYS(Lb + (3 << LG));
    float4 r0 = *(const float4*)(pr + P0), r1 = *(const float4*)(pr + P1);
    float4 r2 = *(const float4*)(pr + P2), r3 = *(const float4*)(pr + P3);
    float4 i0 = *(const float4*)(pi + P0), i1 = *(const float4*)(pi + P1);
    float4 i2 = *(const float4*)(pi + P2), i3 = *(const float4*)(pi + P3);
#define CBTI(CMP, II) { \
    const int e1 = (u0 + II) << (8 - LG); \
    const float w1c = tab[TPHYS(e1)]; \
    const float w1s = tab[272 + TPHYS(e1)]; \
    const float w3c = w1c * w1c - w1s * w1s; \
    const float w3s = 2.f * w1c * w1s; \
    const float m1r = r1.CMP * w3c - i1.CMP * w3s, m1i = i1.CMP * w3c + r1.CMP * w3s; \
    const float s0r = r0.CMP + m1r, s0i = i0.CMP + m1i; \
    const float s1r = r0.CMP - m1r, s1i = i0.CMP - m1i; \
    const float m3r = r3.CMP * w3c - i3.CMP * w3s, m3i = i3.CMP * w3c + r3.CMP * w3s; \
    const float s2r = r2.CMP + m3r, s2i = i2.CMP + m3i; \
    const float s3r = r2.CMP - m3r, s3i = i2.CMP - m3i; \
    const float p2r = s2r * w1c - s2i * w1s, p2i = s2i * w1c + s2r * w1s; \
    const float n3r = s3r * w1c - s3i * w1s, n3i = s3i * w1c + s3r * w1s; \
    const float p3r = -n3i, p3i = n3r; \
    r0.CMP = s0r + p2r; i0.CMP = s0i + p2i; \
    r2.CMP = s0r - p2r; i2.CMP = s0i - p2i; \
    r1.CMP = s1r + p3r; i1.CMP = s1i + p3i; \
    r3.CMP = s1r - p3r; i3.CMP = s1i - p3i; }
    CBTI(x, 0) CBTI(y, 1) CBTI(z, 2) CBTI(w, 3)
#undef CBTI
    *(float4*)(pr + P0) = r0; *(float4*)(pr + P1) = r1;
    *(float4*)(pr + P2) = r2; *(float4*)(pr + P3) = r3;
    *(float4*)(pi + P0) = i0; *(float4*)(pi + P1) = i1;
    *(float4*)(pi + P2) = i2; *(float4*)(pi + P3) = i3;
}

// ---- tail_fused: tail4_fwd (levels 16..2) + unpack + tail4_inv (levels 2..16)
// in ONE LDS round-trip. z published to LDS only for partner visibility; S is
// computed IN-PLACE over the z registers (own side from regs, partner from
// LDS); tail4_inv runs on the registers before the single store.
// LDS op order: [read own] [write z] [read partner] [write final] — same-
// pointer aliasing orders these at compile time; per-wave DS is in-order.
__device__ __forceinline__ void tail_fused(float* __restrict__ pr, float* __restrict__ pi, int lane)
{
    const int Pb = PHYS(lane << 4);
    float4 r0 = *(const float4*)(pr + Pb),      r1 = *(const float4*)(pr + Pb + 4);
    float4 r2 = *(const float4*)(pr + Pb + 8),  r3 = *(const float4*)(pr + Pb + 12);
    float4 i0 = *(const float4*)(pi + Pb),      i1 = *(const float4*)(pi + Pb + 4);
    float4 i2 = *(const float4*)(pi + Pb + 8),  i3 = *(const float4*)(pi + Pb + 12);
    // ---------- forward stage M=16 (levels 16,8): componentwise across quads
#define TCF(CMP, C) { \
    const float w1r = K16C[C], w1i = -K16S[C]; \
    const float w3r = w1r*w1r - w1i*w1i, w3i = 2.f*w1r*w1i; \
    const float t0r = r0.CMP + r2.CMP, t0i = i0.CMP + i2.CMP; \
    const float d2r = r0.CMP - r2.CMP, d2i = i0.CMP - i2.CMP; \
    const float t2r = d2r*w1r - d2i*w1i, t2i = d2i*w1r + d2r*w1i; \
    const float t1r = r1.CMP + r3.CMP, t1i = i1.CMP + i3.CMP; \
    const float d3r = r1.CMP - r3.CMP, d3i = i1.CMP - i3.CMP; \
    const float m3r = d3r*w1r - d3i*w1i, m3i = d3i*w1r + d3r*w1i; \
    const float t3r = m3i, t3i = -m3r; \
    const float a0r = t0r+t1r, a0i = t0i+t1i; \
    const float a1r = t0r-t1r, a1i = t0i-t1i; \
    const float a2r = t2r+t3r, a2i = t2i+t3i; \
    const float a3r = t2r-t3r, a3i = t2i-t3i; \
    r0.CMP = a0r; i0.CMP = a0i; \
    r1.CMP = a1r*w3r - a1i*w3i; i1.CMP = a1i*w3r + a1r*w3i; \
    r2.CMP = a2r; i2.CMP = a2i; \
    r3.CMP = a3r*w3r - a3i*w3i; i3.CMP = a3i*w3r + a3r*w3i; }
    TCF(x,0) TCF(y,1) TCF(z,2) TCF(w,3)
#undef TCF
    // ---------- forward stage M=4 (levels 4,2) within each quad
#define Q4F(RQ, IQ) { \
    const float t0r = RQ.x + RQ.z, t0i = IQ.x + IQ.z; \
    const float t2r = RQ.x - RQ.z, t2i = IQ.x - IQ.z; \
    const float t1r = RQ.y + RQ.w, t1i = IQ.y + IQ.w; \
    const float d3r = RQ.y - RQ.w, d3i = IQ.y - IQ.w; \
    const float t3r = d3i, t3i = -d3r; \
    RQ.x = t0r + t1r; IQ.x = t0i + t1i; \
    RQ.y = t0r - t1r; IQ.y = t0i - t1i; \
    RQ.z = t2r + t3r; IQ.z = t2i + t3i; \
    RQ.w = t2r - t3r; IQ.w = t2i - t3i; }
    Q4F(r0, i0) Q4F(r1, i1) Q4F(r2, i2) Q4F(r3, i3)
#undef Q4F
    // ---------- publish z (other lanes' partner reads need it)
    *(float4*)(pr + Pb) = r0;      *(float4*)(pr + Pb + 4) = r1;
    *(float4*)(pr + Pb + 8) = r2;  *(float4*)(pr + Pb + 12) = r3;
    *(float4*)(pi + Pb) = i0;      *(float4*)(pi + Pb + 4) = i1;
    *(float4*)(pi + Pb + 8) = i2;  *(float4*)(pi + Pb + 12) = i3;
    // ---------- S = Q*conj(K)/1024 in-place (LDS read-only in this phase)
#define UNP(RQ, IQ, QI, CMP, JJ) { \
    const int p  = (lane << 4) + 4*QI + JJ; \
    const int f  = (int)(__brev((unsigned)p) >> 22); \
    const int fb = (1024 - f) & 1023; \
    const int pb = (int)(__brev((unsigned)fb) >> 22); \
    const int Ppb = PHYS(pb); \
    const float brv = pr[Ppb], biv = pi[Ppb]; \
    const float arv = RQ.CMP, aiv = IQ.CMP; \
    const float Qr = 0.5f*(arv + brv), Qi = 0.5f*(aiv - biv); \
    const float Kr = 0.5f*(aiv + biv), Ki = 0.5f*(brv - arv); \
    RQ.CMP = (Qr*Kr + Qi*Ki) * (1.f/1024.f); \
    IQ.CMP = (Qi*Kr - Qr*Ki) * (1.f/1024.f); }
    UNP(r0,i0,0,x,0) UNP(r0,i0,0,y,1) UNP(r0,i0,0,z,2) UNP(r0,i0,0,w,3)
    UNP(r1,i1,1,x,0) UNP(r1,i1,1,y,1) UNP(r1,i1,1,z,2) UNP(r1,i1,1,w,3)
    UNP(r2,i2,2,x,0) UNP(r2,i2,2,y,1) UNP(r2,i2,2,z,2) UNP(r2,i2,2,w,3)
    UNP(r3,i3,3,x,0) UNP(r3,i3,3,y,1) UNP(r3,i3,3,z,2) UNP(r3,i3,3,w,3)
#undef UNP
    // ---------- inverse stage M=4 (levels 2,4), conj (+i)
#define Q4I(RQ, IQ) { \
    const float s0r = RQ.x + RQ.y, s0i = IQ.x + IQ.y; \
    const float s1r = RQ.x - RQ.y, s1i = IQ.x - IQ.y; \
    const float s2r = RQ.z + RQ.w, s2i = IQ.z + IQ.w; \
    const float s3r = RQ.z - RQ.w, s3i = IQ.z - IQ.w; \
    const float p3r = -s3i, p3i = s3r; \
    RQ.x = s0r + s2r; IQ.x = s0i + s2i; \
    RQ.z = s0r - s2r; IQ.z = s0i - s2i; \
    RQ.y = s1r + p3r; IQ.y = s1i + p3i; \
    RQ.w = s1r - p3r; IQ.w = s1i - p3i; }
    Q4I(r0, i0) Q4I(r1, i1) Q4I(r2, i2) Q4I(r3, i3)
#undef Q4I
    // ---------- inverse stage M=16 (levels 8,16): componentwise, conj
#define TCI(CMP, C) { \
    const float w1r = K16C[C], w1i = K16S[C]; \
    const float w3r = w1r*w1r - w1i*w1i, w3i = 2.f*w1r*w1i; \
    const float m1r = r1.CMP*w3r - i1.CMP*w3i, m1i = i1.CMP*w3r + r1.CMP*w3i; \
    const float s0r = r0.CMP + m1r, s0i = i0.CMP + m1i; \
    const float s1r = r0.CMP - m1r, s1i = i0.CMP - m1i; \
    const float m3r = r3.CMP*w3r - i3.CMP*w3i, m3i = i3.CMP*w3r + r3.CMP*w3i; \
    const float s2r = r2.CMP + m3r, s2i = i2.CMP + m3i; \
    const float s3r = r2.CMP - m3r, s3i = i2.CMP - m3i; \
    const float t2r = s2r*w1r - s2i*w1i, t2i = s2i*w1r + s2r*w1i; \
    const float n3r = s3r*w1r - s3i*w1i, n3i = s3i*w1r + s3r*w1i; \
    const float t3r = -n3i, t3i = n3r; \
    r0.CMP = s0r + t2r; i0.CMP = s0i + t2i; \
    r2.CMP = s0r - t2r; i2.CMP = s0i - t2i; \
    r1.CMP = s1r + t3r; i1.CMP = s1i + t3i; \
    r3.CMP = s1r - t3r; i3.CMP = s1i - t3i; }
    TCI(x,0) TCI(y,1) TCI(z,2) TCI(w,3)
#undef TCI
    *(float4*)(pr + Pb) = r0;      *(float4*)(pr + Pb + 4) = r1;
    *(float4*)(pr + Pb + 8) = r2;  *(float4*)(pr + Pb + 12) = r3;
    *(float4*)(pi + Pb) = i0;      *(float4*)(pi + Pb + 4) = i1;
    *(float4*)(pi + Pb + 8) = i2;  *(float4*)(pi + Pb + 12) = i3;
}

// ---------------- Kernel A: FFT autocorrelation (LDS-resident) ----------------
// grid (NE/8, NH, NB), block 512 = 8 waves; 8 series/block, one per wave.
// Passes: head4 | mid | [tail_fused] | mid_inv | head4_inv  (5 round-trips,
// was 7 in round 10).
__global__ __launch_bounds__(512) void fftcorr_kernel(
    const float* __restrict__ q, const float* __restrict__ k,
    float* __restrict__ corr_out, float* __restrict__ ws_mean)
{
    extern __shared__ float LDSF[];
    const int tid = threadIdx.x;
    const int n = blockIdx.z, h = blockIdx.y, e0 = blockIdx.x * 8;

    if (tid < 256) {
        float sv, cv;
        __sincosf((float)tid * (6.2831853071795865f / 1024.f), &sv, &cv);
        LDSF[TBO + TPHYS(tid)] = cv;
        LDSF[TBO + 272 + TPHYS(tid)] = sv;
    }

    // stage: z.re-plane = q, z.im-plane = k (float4 global loads; 4096 total)
    {
#pragma unroll
        for (int c = 0; c < 8; ++c) {
            const int idx = c * 512 + tid;
            const int isk = idx >> 11;
            const int rem = idx & 2047;
            const int t  = rem >> 1;
            const int eh = rem & 1;
            const float* __restrict__ src = isk ? k : q;
            const size_t g = ((((size_t)n * L_SEQ + t) * NH + h) * NE) + e0 + 4 * eh;
            const float4 v = *reinterpret_cast<const float4*>(src + g);
            const int ph = PHYS(t);
            LDSF[(size_t)(2 * (4 * eh + 0) + isk) * PS + ph] = v.x;
            LDSF[(size_t)(2 * (4 * eh + 1) + isk) * PS + ph] = v.y;
            LDSF[(size_t)(2 * (4 * eh + 2) + isk) * PS + ph] = v.z;
            LDSF[(size_t)(2 * (4 * eh + 3) + isk) * PS + ph] = v.w;
        }
    }
    __syncthreads();

    const int w = tid >> 6;
    const int lane = tid & 63;
    const float* tab = LDSF + TBO;

    {
        float* pr = LDSF + (size_t)(2 * w) * PS;
        float* pi = pr + PS;

        head4_fwd(pr, pi, tab, lane);       // levels 1024,512,256,128
        dif_dstage<4>(pr, pi, tab, lane);   // levels 64,32
        tail_fused(pr, pi, lane);           // levels 16..2 | S | levels 2..16
        dit_dstage<4>(pr, pi, tab, lane);   // levels 32,64
        head4_inv(pr, pi, tab, lane);       // levels 128,256,512,1024
    }
    __syncthreads();

    // writeout: per-lane float4 across 4 re-planes + 32B global write + mean
    {
#pragma unroll
        for (int c = 0; c < 4; ++c) {
            const int f4idx = c * 512 + tid;
            const int l  = f4idx >> 1;
            const int j4 = f4idx & 1;
            const int ph = PHYS(l);
            float4 v;
            v.x = LDSF[(size_t)(2 * (4 * j4 + 0)) * PS + ph];
            v.y = LDSF[(size_t)(2 * (4 * j4 + 1)) * PS + ph];
            v.z = LDSF[(size_t)(2 * (4 * j4 + 2)) * PS + ph];
            v.w = LDSF[(size_t)(2 * (4 * j4 + 3)) * PS + ph];
            *reinterpret_cast<float4*>(
                corr_out + ((((size_t)n * L_SEQ + l) * NH + h) * NE) + e0 + 4 * j4) = v;
            const float esum = v.x + v.y + v.z + v.w;
            const float tot = esum + __shfl_xor(esum, 1, 64);
            if ((tid & 1) == 0) atomicAdd(&ws_mean[n * L_SEQ + l], tot);
        }
    }
}

// ---------------- Kernel B: top-6 lags + per-n softmax ----------------
__global__ __launch_bounds__(1024) void topk_softmax_kernel(
    const float* __restrict__ ws_mean, int* __restrict__ ws_idx,
    float* __restrict__ ws_w)
{
    __shared__ float val[1024];
    __shared__ float rv[1024];
    __shared__ int   ri[1024];
    __shared__ int   sel[TOPK];
    const int tid = threadIdx.x;

    float s = 0.f;
    for (int n = 0; n < NB; ++n) s += ws_mean[n * L_SEQ + tid];
    val[tid] = s;
    __syncthreads();

    for (int kk = 0; kk < TOPK; ++kk) {
        rv[tid] = val[tid];
        ri[tid] = tid;
        __syncthreads();
        for (int off = 512; off > 0; off >>= 1) {
            if (tid < off) {
                const float a = rv[tid], b = rv[tid + off];
                const int ia = ri[tid], ib = ri[tid + off];
                if (b > a || (b == a && ib < ia)) { rv[tid] = b; ri[tid] = ib; }
            }
            __syncthreads();
        }
        if (tid == 0) { sel[kk] = ri[0]; val[ri[0]] = -1e30f; }
        __syncthreads();
    }
    if (tid < TOPK) ws_idx[tid] = sel[tid];

    if (tid < NB) {
        float wv[TOPK];
        float m = -1e30f;
        for (int kk = 0; kk < TOPK; ++kk) {
            wv[kk] = ws_mean[tid * L_SEQ + sel[kk]] * (1.f / (NH * NE));
            m = fmaxf(m, wv[kk]);
        }
        float sum = 0.f;
        for (int kk = 0; kk < TOPK; ++kk) { wv[kk] = expf(wv[kk] - m); sum += wv[kk]; }
        const float inv = 1.f / sum;
        for (int kk = 0; kk < TOPK; ++kk) ws_w[tid * 8 + kk] = wv[kk] * inv;
    }
}

// ---------------- Kernel C: lag-gather weighted sum of v ----------------
__global__ __launch_bounds__(256) void gather_kernel(
    const float* __restrict__ v, const int* __restrict__ ws_idx,
    const float* __restrict__ ws_w, float* __restrict__ out)
{
    const int n = blockIdx.y;
    const int idx4 = blockIdx.x * 256 + threadIdx.x;
    const int l = idx4 >> 7;
    const int r = idx4 & 127;
    const float* wrow = ws_w + n * 8;

    float4 acc = make_float4(0.f, 0.f, 0.f, 0.f);
#pragma unroll
    for (int kk = 0; kk < TOPK; ++kk) {
        const int t = (l + ws_idx[kk]) & (L_SEQ - 1);
        const float4 vv = *reinterpret_cast<const float4*>(
            v + (((size_t)n * L_SEQ + t) * (NH * NE)) + r * 4);
        const float wk = wrow[kk];
        acc.x = fmaf(wk, vv.x, acc.x);
        acc.y = fmaf(wk, vv.y, acc.y);
        acc.z = fmaf(wk, vv.z, acc.z);
        acc.w = fmaf(wk, vv.w, acc.w);
    }
    *reinterpret_cast<float4*>(out + ((size_t)n * L_SEQ + l) * (NH * NE) + r * 4) = acc;
}

extern "C" void kernel_launch(void* const* d_in, const int* in_sizes, int n_in,
                              void* d_out, int out_size, void* d_ws, size_t ws_size,
                              hipStream_t stream)
{
    const float* q = (const float*)d_in[0];
    const float* k = (const float*)d_in[1];
    const float* v = (const float*)d_in[2];
    float* out = (float*)d_out;
    float* corr_out = out + (size_t)NB * L_SEQ * NH * NE;

    float* ws_mean = (float*)d_ws;                              // 32*1024 f32
    int*   ws_idx  = (int*)((char*)d_ws + 131072);              // 6 ints
    float* ws_w    = (float*)((char*)d_ws + 131072 + 256);      // 32*8 f32

    hipMemsetAsync(d_ws, 0, 131072, stream);
    const size_t lds_bytes = (size_t)LDS_FLOATS * sizeof(float);   // 75,904 B
    fftcorr_kernel<<<dim3(NE / 8, NH, NB), 512, lds_bytes, stream>>>(q, k, corr_out, ws_mean);
    topk_softmax_kernel<<<1, 1024, 0, stream>>>(ws_mean, ws_idx, ws_w);
    gather_kernel<<<dim3(512, NB), 256, 0, stream>>>(v, ws_idx, ws_w, out);
}

// Round 14
// 188.576 us; speedup vs baseline: 1.0113x; 1.0055x over previous
//
#include <hip/hip_runtime.h>
#include <hip/hip_fp16.h>

#define L_SEQ 1024
#define NB 32
#define NH 8
#define NE 64
#define TOPK 6

typedef unsigned int u32;

// LDS geometry (round 14: fp16x2-packed complex planes).
// 8 series-planes of 1024 complex packed as half2 in u32; 32 groups of 32 at
// stride 36 (12.5% pad). 8*1152*4 B + fp32 table 2176 B = 39,040 B ->
// 4 blocks/CU = 32 waves/CU (2x round 13's fp32-plane cap of ~16).
#define PSC  1152                 // u32 per packed series plane
#define TBOU (8 * PSC)            // 9216 — table offset (in u32 units)
#define PHYS(L)  (36 * ((L) >> 5) + ((L) & 31))
#define TPHYS(E) ((E) + ((E) >> 4))
#define LDS_BYTES ((TBOU + 544) * 4)   // 39,040 B

// W16^j = (cos(pi j/8), sin(pi j/8)), j = 0..3
constexpr float K16C[4] = {1.f, 0.92387953f, 0.70710678f, 0.38268343f};
constexpr float K16S[4] = {0.f, 0.38268343f, 0.70710678f, 0.92387953f};

// fp16x2 pack/unpack (LDS-resident state only; all math in fp32 registers)
__device__ __forceinline__ u32 PK(float r, float i) {
    union { __half2 h; u32 u; } c;
    c.h = __floats2half2_rn(r, i);
    return c.u;
}
__device__ __forceinline__ float2 UPK(u32 u) {
    union { u32 u; __half2 h; } c;
    c.u = u;
    return __half22float2(c.h);
}
#define UQ4(Z,R,I) { const float2 a_=UPK(Z.x), b_=UPK(Z.y), c_=UPK(Z.z), d_=UPK(Z.w); \
    R = make_float4(a_.x,b_.x,c_.x,d_.x); I = make_float4(a_.y,b_.y,c_.y,d_.y); }
#define PQ4(Z,R,I) { Z.x=PK(R.x,I.x); Z.y=PK(R.y,I.y); Z.z=PK(R.z,I.z); Z.w=PK(R.w,I.w); }

// radix-4 fused butterfly (two DIF levels M, M/2) on named scalars xr#/xi#.
#define BTF4F(A,B,C,D) { \
    const float t0r = xr##A + xr##C, t0i = xi##A + xi##C; \
    const float d2r = xr##A - xr##C, d2i = xi##A - xi##C; \
    const float t2r = d2r*w1r - d2i*w1i, t2i = d2i*w1r + d2r*w1i; \
    const float t1r = xr##B + xr##D, t1i = xi##B + xi##D; \
    const float d3r = xr##B - xr##D, d3i = xi##B - xi##D; \
    const float m3r = d3r*w1r - d3i*w1i, m3i = d3i*w1r + d3r*w1i; \
    const float t3r = m3i, t3i = -m3r; \
    const float a0r = t0r + t1r, a0i = t0i + t1i; \
    const float a1r = t0r - t1r, a1i = t0i - t1i; \
    const float a2r = t2r + t3r, a2i = t2i + t3i; \
    const float a3r = t2r - t3r, a3i = t2i - t3i; \
    xr##A = a0r; xi##A = a0i; \
    xr##B = a1r*w3r - a1i*w3i; xi##B = a1i*w3r + a1r*w3i; \
    xr##C = a2r; xi##C = a2i; \
    xr##D = a3r*w3r - a3i*w3i; xi##D = a3i*w3r + a3r*w3i; }

#define BTF4I(A,B,C,D) { \
    const float m1r = xr##B*w3r - xi##B*w3i, m1i = xi##B*w3r + xr##B*w3i; \
    const float s0r = xr##A + m1r, s0i = xi##A + m1i; \
    const float s1r = xr##A - m1r, s1i = xi##A - m1i; \
    const float m3r = xr##D*w3r - xi##D*w3i, m3i = xi##D*w3r + xr##D*w3i; \
    const float s2r = xr##C + m3r, s2i = xi##C + m3i; \
    const float s3r = xr##C - m3r, s3i = xi##C - m3i; \
    const float t2r = s2r*w1r - s2i*w1i, t2i = s2i*w1r + s2r*w1i; \
    const float n3r = s3r*w1r - s3i*w1i, n3i = s3i*w1r + s3r*w1i; \
    const float t3r = -n3i, t3i = n3r; \
    xr##A = s0r + t2r; xi##A = s0i + t2i; \
    xr##C = s0r - t2r; xi##C = s0i - t2i; \
    xr##B = s1r + t3r; xi##B = s1i + t3i; \
    xr##D = s1r - t3r; xi##D = s1i - t3i; }

// ---- head4: levels 1024,512,256,128 in one pass; lane owns {lane + 64j}.
__device__ __forceinline__ void head4_fwd(u32* __restrict__ pc,
                                          const float* __restrict__ tab, int lane)
{
    const int A0 = 36 * (lane >> 5) + (lane & 31);
    const float tc = tab[TPHYS(lane)];
    const float ts = tab[272 + TPHYS(lane)];
    const float wbr = tc, wbi = -ts;
    const float w2r = wbr*wbr - wbi*wbi, w2i = 2.f*wbr*wbi;
    const float w4r = w2r*w2r - w2i*w2i, w4i = 2.f*w2r*w2i;
    const float w8r = w4r*w4r - w4i*w4i, w8i = 2.f*w4r*w4i;
#define HD(J) float xr##J, xi##J; { const float2 z_ = UPK(pc[A0 + 72*J]); xr##J = z_.x; xi##J = z_.y; }
    HD(0) HD(1) HD(2) HD(3) HD(4) HD(5) HD(6) HD(7)
    HD(8) HD(9) HD(10) HD(11) HD(12) HD(13) HD(14) HD(15)
#undef HD
#define STA(JA,JB,JC,JD,J16) { \
    const float w1r = wbr*K16C[J16] + wbi*K16S[J16]; \
    const float w1i = wbi*K16C[J16] - wbr*K16S[J16]; \
    const float w3r = w1r*w1r - w1i*w1i, w3i = 2.f*w1r*w1i; \
    BTF4F(JA,JB,JC,JD) }
    STA(0,4,8,12,0) STA(1,5,9,13,1) STA(2,6,10,14,2) STA(3,7,11,15,3)
#undef STA
    {
        const float w1r = w4r, w1i = w4i, w3r = w8r, w3i = w8i;
        BTF4F(0,1,2,3) BTF4F(4,5,6,7) BTF4F(8,9,10,11) BTF4F(12,13,14,15)
    }
#define HS(J) pc[A0 + 72*J] = PK(xr##J, xi##J);
    HS(0) HS(1) HS(2) HS(3) HS(4) HS(5) HS(6) HS(7)
    HS(8) HS(9) HS(10) HS(11) HS(12) HS(13) HS(14) HS(15)
#undef HS
}

__device__ __forceinline__ void head4_inv(u32* __restrict__ pc,
                                          const float* __restrict__ tab, int lane)
{
    const int A0 = 36 * (lane >> 5) + (lane & 31);
    const float tc = tab[TPHYS(lane)];
    const float ts = tab[272 + TPHYS(lane)];
    const float vbr = tc, vbi = ts;
    const float v2r = vbr*vbr - vbi*vbi, v2i = 2.f*vbr*vbi;
    const float v4r = v2r*v2r - v2i*v2i, v4i = 2.f*v2r*v2i;
    const float v8r = v4r*v4r - v4i*v4i, v8i = 2.f*v4r*v4i;
#define HD(J) float xr##J, xi##J; { const float2 z_ = UPK(pc[A0 + 72*J]); xr##J = z_.x; xi##J = z_.y; }
    HD(0) HD(1) HD(2) HD(3) HD(4) HD(5) HD(6) HD(7)
    HD(8) HD(9) HD(10) HD(11) HD(12) HD(13) HD(14) HD(15)
#undef HD
    {
        const float w1r = v4r, w1i = v4i, w3r = v8r, w3i = v8i;
        BTF4I(0,1,2,3) BTF4I(4,5,6,7) BTF4I(8,9,10,11) BTF4I(12,13,14,15)
    }
#define STB(JA,JB,JC,JD,J16) { \
    const float w1r = vbr*K16C[J16] - vbi*K16S[J16]; \
    const float w1i = vbi*K16C[J16] + vbr*K16S[J16]; \
    const float w3r = w1r*w1r - w1i*w1i, w3i = 2.f*w1r*w1i; \
    BTF4I(JA,JB,JC,JD) }
    STB(0,4,8,12,0) STB(1,5,9,13,1) STB(2,6,10,14,2) STB(3,7,11,15,3)
#undef STB
#define HS(J) pc[A0 + 72*J] = PK(xr##J, xi##J);
    HS(0) HS(1) HS(2) HS(3) HS(4) HS(5) HS(6) HS(7)
    HS(8) HS(9) HS(10) HS(11) HS(12) HS(13) HS(14) HS(15)
#undef HS
}

// ---- mid stage (levels 64,32): packed-quad variant of round-9 LG=4 dstage
__device__ __forceinline__ void dif_mid(u32* __restrict__ pc,
                                        const float* __restrict__ tab, int lane)
{
    const int b0 = lane << 2;
    const int u0 = b0 & 15;
    const int Lb = ((b0 >> 4) << 6) + u0;
    const int P0 = PHYS(Lb), P1 = PHYS(Lb + 16), P2 = PHYS(Lb + 32), P3 = PHYS(Lb + 48);
    uint4 z0 = *(const uint4*)(pc + P0), z1 = *(const uint4*)(pc + P1);
    uint4 z2 = *(const uint4*)(pc + P2), z3 = *(const uint4*)(pc + P3);
    float4 r0, i0, r1, i1, r2, i2, r3, i3;
    UQ4(z0, r0, i0) UQ4(z1, r1, i1) UQ4(z2, r2, i2) UQ4(z3, r3, i3)
#define CBTF(CMP, II) { \
    const int e1 = (u0 + II) << 4; \
    const float w1c = tab[TPHYS(e1)]; \
    const float w1s = tab[272 + TPHYS(e1)]; \
    const float w3c = w1c * w1c - w1s * w1s; \
    const float w3s = 2.f * w1c * w1s; \
    const float t0r = r0.CMP + r2.CMP, t0i = i0.CMP + i2.CMP; \
    const float d2r = r0.CMP - r2.CMP, d2i = i0.CMP - i2.CMP; \
    const float t2r = d2r * w1c + d2i * w1s, t2i = d2i * w1c - d2r * w1s; \
    const float t1r = r1.CMP + r3.CMP, t1i = i1.CMP + i3.CMP; \
    const float d3r = r1.CMP - r3.CMP, d3i = i1.CMP - i3.CMP; \
    const float m3r = d3r * w1c + d3i * w1s, m3i = d3i * w1c - d3r * w1s; \
    const float t3r = m3i, t3i = -m3r; \
    const float a0r = t0r + t1r, a0i = t0i + t1i; \
    const float a1r = t0r - t1r, a1i = t0i - t1i; \
    const float a2r = t2r + t3r, a2i = t2i + t3i; \
    const float a3r = t2r - t3r, a3i = t2i - t3i; \
    r0.CMP = a0r;                     i0.CMP = a0i; \
    r1.CMP = a1r * w3c + a1i * w3s;   i1.CMP = a1i * w3c - a1r * w3s; \
    r2.CMP = a2r;                     i2.CMP = a2i; \
    r3.CMP = a3r * w3c + a3i * w3s;   i3.CMP = a3i * w3c - a3r * w3s; }
    CBTF(x, 0) CBTF(y, 1) CBTF(z, 2) CBTF(w, 3)
#undef CBTF
    PQ4(z0, r0, i0) PQ4(z1, r1, i1) PQ4(z2, r2, i2) PQ4(z3, r3, i3)
    *(uint4*)(pc + P0) = z0; *(uint4*)(pc + P1) = z1;
    *(uint4*)(pc + P2) = z2; *(uint4*)(pc + P3) = z3;
}

__device__ __forceinline__ void dit_mid(u32* __restrict__ pc,
                                        const float* __restrict__ tab, int lane)
{
    const int b0 = lane << 2;
    const int u0 = b0 & 15;
    const int Lb = ((b0 >> 4) << 6) + u0;
    const int P0 = PHYS(Lb), P1 = PHYS(Lb + 16), P2 = PHYS(Lb + 32), P3 = PHYS(Lb + 48);
    uint4 z0 = *(const uint4*)(pc + P0), z1 = *(const uint4*)(pc + P1);
    uint4 z2 = *(const uint4*)(pc + P2), z3 = *(const uint4*)(pc + P3);
    float4 r0, i0, r1, i1, r2, i2, r3, i3;
    UQ4(z0, r0, i0) UQ4(z1, r1, i1) UQ4(z2, r2, i2) UQ4(z3, r3, i3)
#define CBTI(CMP, II) { \
    const int e1 = (u0 + II) << 4; \
    const float w1c = tab[TPHYS(e1)]; \
    const float w1s = tab[272 + TPHYS(e1)]; \
    const float w3c = w1c * w1c - w1s * w1s; \
    const float w3s = 2.f * w1c * w1s; \
    const float m1r = r1.CMP * w3c - i1.CMP * w3s, m1i = i1.CMP * w3c + r1.CMP * w3s; \
    const float s0r = r0.CMP + m1r, s0i = i0.CMP + m1i; \
    const float s1r = r0.CMP - m1r, s1i = i0.CMP - m1i; \
    const float m3r = r3.CMP * w3c - i3.CMP * w3s, m3i = i3.CMP * w3c + r3.CMP * w3s; \
    const float s2r = r2.CMP + m3r, s2i = i2.CMP + m3i; \
    const float s3r = r2.CMP - m3r, s3i = i2.CMP - m3i; \
    const float p2r = s2r * w1c - s2i * w1s, p2i = s2i * w1c + s2r * w1s; \
    const float n3r = s3r * w1c - s3i * w1s, n3i = s3i * w1c + s3r * w1s; \
    const float p3r = -n3i, p3i = n3r; \
    r0.CMP = s0r + p2r; i0.CMP = s0i + p2i; \
    r2.CMP = s0r - p2r; i2.CMP = s0i - p2i; \
    r1.CMP = s1r + p3r; i1.CMP = s1i + p3i; \
    r3.CMP = s1r - p3r; i3.CMP = s1i - p3i; }
    CBTI(x, 0) CBTI(y, 1) CBTI(z, 2) CBTI(w, 3)
#undef CBTI
    PQ4(z0, r0, i0) PQ4(z1, r1, i1) PQ4(z2, r2, i2) PQ4(z3, r3, i3)
    *(uint4*)(pc + P0) = z0; *(uint4*)(pc + P1) = z1;
    *(uint4*)(pc + P2) = z2; *(uint4*)(pc + P3) = z3;
}

// ---- tail_fused: levels 16..2 | S=Q*conj(K)/1024 | levels 2..16, one trip.
__device__ __forceinline__ void tail_fused(u32* __restrict__ pc, int lane)
{
    const int Pb = PHYS(lane << 4);
    uint4 z0 = *(const uint4*)(pc + Pb),     z1 = *(const uint4*)(pc + Pb + 4);
    uint4 z2 = *(const uint4*)(pc + Pb + 8), z3 = *(const uint4*)(pc + Pb + 12);
    float4 r0, i0, r1, i1, r2, i2, r3, i3;
    UQ4(z0, r0, i0) UQ4(z1, r1, i1) UQ4(z2, r2, i2) UQ4(z3, r3, i3)
#define TCF(CMP, C) { \
    const float w1r = K16C[C], w1i = -K16S[C]; \
    const float w3r = w1r*w1r - w1i*w1i, w3i = 2.f*w1r*w1i; \
    const float t0r = r0.CMP + r2.CMP, t0i = i0.CMP + i2.CMP; \
    const float d2r = r0.CMP - r2.CMP, d2i = i0.CMP - i2.CMP; \
    const float t2r = d2r*w1r - d2i*w1i, t2i = d2i*w1r + d2r*w1i; \
    const float t1r = r1.CMP + r3.CMP, t1i = i1.CMP + i3.CMP; \
    const float d3r = r1.CMP - r3.CMP, d3i = i1.CMP - i3.CMP; \
    const float m3r = d3r*w1r - d3i*w1i, m3i = d3i*w1r + d3r*w1i; \
    const float t3r = m3i, t3i = -m3r; \
    const float a0r = t0r+t1r, a0i = t0i+t1i; \
    const float a1r = t0r-t1r, a1i = t0i-t1i; \
    const float a2r = t2r+t3r, a2i = t2i+t3i; \
    const float a3r = t2r-t3r, a3i = t2i-t3i; \
    r0.CMP = a0r; i0.CMP = a0i; \
    r1.CMP = a1r*w3r - a1i*w3i; i1.CMP = a1i*w3r + a1r*w3i; \
    r2.CMP = a2r; i2.CMP = a2i; \
    r3.CMP = a3r*w3r - a3i*w3i; i3.CMP = a3i*w3r + a3r*w3i; }
    TCF(x,0) TCF(y,1) TCF(z,2) TCF(w,3)
#undef TCF
#define Q4F(RQ, IQ) { \
    const float t0r = RQ.x + RQ.z, t0i = IQ.x + IQ.z; \
    const float t2r = RQ.x - RQ.z, t2i = IQ.x - IQ.z; \
    const float t1r = RQ.y + RQ.w, t1i = IQ.y + IQ.w; \
    const float d3r = RQ.y - RQ.w, d3i = IQ.y - IQ.w; \
    const float t3r = d3i, t3i = -d3r; \
    RQ.x = t0r + t1r; IQ.x = t0i + t1i; \
    RQ.y = t0r - t1r; IQ.y = t0i - t1i; \
    RQ.z = t2r + t3r; IQ.z = t2i + t3i; \
    RQ.w = t2r - t3r; IQ.w = t2i - t3i; }
    Q4F(r0, i0) Q4F(r1, i1) Q4F(r2, i2) Q4F(r3, i3)
#undef Q4F
    // publish packed z for partner visibility
    PQ4(z0, r0, i0) PQ4(z1, r1, i1) PQ4(z2, r2, i2) PQ4(z3, r3, i3)
    *(uint4*)(pc + Pb) = z0;     *(uint4*)(pc + Pb + 4) = z1;
    *(uint4*)(pc + Pb + 8) = z2; *(uint4*)(pc + Pb + 12) = z3;
    // S in-place (own side fp32 regs; partner single packed read)
#define UNP(RQ, IQ, QI, CMP, JJ) { \
    const int p  = (lane << 4) + 4*QI + JJ; \
    const int f  = (int)(__brev((unsigned)p) >> 22); \
    const int fb = (1024 - f) & 1023; \
    const int pb = (int)(__brev((unsigned)fb) >> 22); \
    const float2 b_ = UPK(pc[PHYS(pb)]); \
    const float arv = RQ.CMP, aiv = IQ.CMP; \
    const float Qr = 0.5f*(arv + b_.x), Qi = 0.5f*(aiv - b_.y); \
    const float Kr = 0.5f*(aiv + b_.y), Ki = 0.5f*(b_.x - arv); \
    RQ.CMP = (Qr*Kr + Qi*Ki) * (1.f/1024.f); \
    IQ.CMP = (Qi*Kr - Qr*Ki) * (1.f/1024.f); }
    UNP(r0,i0,0,x,0) UNP(r0,i0,0,y,1) UNP(r0,i0,0,z,2) UNP(r0,i0,0,w,3)
    UNP(r1,i1,1,x,0) UNP(r1,i1,1,y,1) UNP(r1,i1,1,z,2) UNP(r1,i1,1,w,3)
    UNP(r2,i2,2,x,0) UNP(r2,i2,2,y,1) UNP(r2,i2,2,z,2) UNP(r2,i2,2,w,3)
    UNP(r3,i3,3,x,0) UNP(r3,i3,3,y,1) UNP(r3,i3,3,z,2) UNP(r3,i3,3,w,3)
#undef UNP
#define Q4I(RQ, IQ) { \
    const float s0r = RQ.x + RQ.y, s0i = IQ.x + IQ.y; \
    const float s1r = RQ.x - RQ.y, s1i = IQ.x - IQ.y; \
    const float s2r = RQ.z + RQ.w, s2i = IQ.z + IQ.w; \
    const float s3r = RQ.z - RQ.w, s3i = IQ.z - IQ.w; \
    const float p3r = -s3i, p3i = s3r; \
    RQ.x = s0r + s2r; IQ.x = s0i + s2i; \
    RQ.z = s0r - s2r; IQ.z = s0i - s2i; \
    RQ.y = s1r + p3r; IQ.y = s1i + p3i; \
    RQ.w = s1r - p3r; IQ.w = s1i - p3i; }
    Q4I(r0, i0) Q4I(r1, i1) Q4I(r2, i2) Q4I(r3, i3)
#undef Q4I
#define TCI(CMP, C) { \
    const float w1r = K16C[C], w1i = K16S[C]; \
    const float w3r = w1r*w1r - w1i*w1i, w3i = 2.f*w1r*w1i; \
    const float m1r = r1.CMP*w3r - i1.CMP*w3i, m1i = i1.CMP*w3r + r1.CMP*w3i; \
    const float s0r = r0.CMP + m1r, s0i = i0.CMP + m1i; \
    const float s1r = r0.CMP - m1r, s1i = i0.CMP - m1i; \
    const float m3r = r3.CMP*w3r - i3.CMP*w3i, m3i = i3.CMP*w3r + r3.CMP*w3i; \
    const float s2r = r2.CMP + m3r, s2i = i2.CMP + m3i; \
    const float s3r = r2.CMP - m3r, s3i = i2.CMP - m3i; \
    const float t2r = s2r*w1r - s2i*w1i, t2i = s2i*w1r + s2r*w1i; \
    const float n3r = s3r*w1r - s3i*w1i, n3i = s3i*w1r + s3r*w1i; \
    const float t3r = -n3i, t3i = n3r; \
    r0.CMP = s0r + t2r; i0.CMP = s0i + t2i; \
    r2.CMP = s0r - t2r; i2.CMP = s0i - t2i; \
    r1.CMP = s1r + t3r; i1.CMP = s1i + t3i; \
    r3.CMP = s1r - t3r; i3.CMP = s1i - t3i; }
    TCI(x,0) TCI(y,1) TCI(z,2) TCI(w,3)
#undef TCI
    PQ4(z0, r0, i0) PQ4(z1, r1, i1) PQ4(z2, r2, i2) PQ4(z3, r3, i3)
    *(uint4*)(pc + Pb) = z0;     *(uint4*)(pc + Pb + 4) = z1;
    *(uint4*)(pc + Pb + 8) = z2; *(uint4*)(pc + Pb + 12) = z3;
}

// ---------------- Kernel A: FFT autocorrelation (fp16x2 LDS-resident) --------
// grid (NE/8, NH, NB), block 512 = 8 waves; 8 series/block, one per wave.
__global__ __launch_bounds__(512) void fftcorr_kernel(
    const float* __restrict__ q, const float* __restrict__ k,
    float* __restrict__ corr_out, float* __restrict__ ws_mean)
{
    extern __shared__ u32 LDSU[];
    float* tabf = (float*)(LDSU + TBOU);
    const int tid = threadIdx.x;
    const int n = blockIdx.z, h = blockIdx.y, e0 = blockIdx.x * 8;

    if (tid < 256) {
        float sv, cv;
        __sincosf((float)tid * (6.2831853071795865f / 1024.f), &sv, &cv);
        tabf[TPHYS(tid)] = cv;
        tabf[272 + TPHYS(tid)] = sv;
    }

    // staging: z = q + i*k packed at source; 4 b32 LDS writes per (t, e-quad)
    {
#pragma unroll
        for (int c = 0; c < 4; ++c) {
            const int idx = c * 512 + tid;        // 0..2047
            const int eh = idx & 1;
            const int t  = idx >> 1;
            const size_t g = ((((size_t)n * L_SEQ + t) * NH + h) * NE) + e0 + 4 * eh;
            const float4 qv = *reinterpret_cast<const float4*>(q + g);
            const float4 kv = *reinterpret_cast<const float4*>(k + g);
            const int ph = PHYS(t);
            LDSU[(size_t)(4 * eh + 0) * PSC + ph] = PK(qv.x, kv.x);
            LDSU[(size_t)(4 * eh + 1) * PSC + ph] = PK(qv.y, kv.y);
            LDSU[(size_t)(4 * eh + 2) * PSC + ph] = PK(qv.z, kv.z);
            LDSU[(size_t)(4 * eh + 3) * PSC + ph] = PK(qv.w, kv.w);
        }
    }
    __syncthreads();

    const int w = tid >> 6;
    const int lane = tid & 63;

    {
        u32* pc = LDSU + (size_t)w * PSC;
        head4_fwd(pc, tabf, lane);   // levels 1024,512,256,128
        dif_mid(pc, tabf, lane);     // levels 64,32
        tail_fused(pc, lane);        // levels 16..2 | S | levels 2..16
        dit_mid(pc, tabf, lane);     // levels 32,64
        head4_inv(pc, tabf, lane);   // levels 128,256,512,1024
    }
    __syncthreads();

    // writeout: assemble float4 from 4 planes' re-halves + mean partials
    {
#pragma unroll
        for (int c = 0; c < 4; ++c) {
            const int f4idx = c * 512 + tid;
            const int l  = f4idx >> 1;
            const int j4 = f4idx & 1;
            const int ph = PHYS(l);
            float4 v;
            v.x = UPK(LDSU[(size_t)(4 * j4 + 0) * PSC + ph]).x;
            v.y = UPK(LDSU[(size_t)(4 * j4 + 1) * PSC + ph]).x;
            v.z = UPK(LDSU[(size_t)(4 * j4 + 2) * PSC + ph]).x;
            v.w = UPK(LDSU[(size_t)(4 * j4 + 3) * PSC + ph]).x;
            *reinterpret_cast<float4*>(
                corr_out + ((((size_t)n * L_SEQ + l) * NH + h) * NE) + e0 + 4 * j4) = v;
            const float esum = v.x + v.y + v.z + v.w;
            const float tot = esum + __shfl_xor(esum, 1, 64);
            if ((tid & 1) == 0) atomicAdd(&ws_mean[n * L_SEQ + l], tot);
        }
    }
}

// ---------------- Kernel B: top-6 lags + per-n softmax ----------------
__global__ __launch_bounds__(1024) void topk_softmax_kernel(
    const float* __restrict__ ws_mean, int* __restrict__ ws_idx,
    float* __restrict__ ws_w)
{
    __shared__ float val[1024];
    __shared__ float rv[1024];
    __shared__ int   ri[1024];
    __shared__ int   sel[TOPK];
    const int tid = threadIdx.x;

    float s = 0.f;
    for (int n = 0; n < NB; ++n) s += ws_mean[n * L_SEQ + tid];
    val[tid] = s;
    __syncthreads();

    for (int kk = 0; kk < TOPK; ++kk) {
        rv[tid] = val[tid];
        ri[tid] = tid;
        __syncthreads();
        for (int off = 512; off > 0; off >>= 1) {
            if (tid < off) {
                const float a = rv[tid], b = rv[tid + off];
                const int ia = ri[tid], ib = ri[tid + off];
                if (b > a || (b == a && ib < ia)) { rv[tid] = b; ri[tid] = ib; }
            }
            __syncthreads();
        }
        if (tid == 0) { sel[kk] = ri[0]; val[ri[0]] = -1e30f; }
        __syncthreads();
    }
    if (tid < TOPK) ws_idx[tid] = sel[tid];

    if (tid < NB) {
        float wv[TOPK];
        float m = -1e30f;
        for (int kk = 0; kk < TOPK; ++kk) {
            wv[kk] = ws_mean[tid * L_SEQ + sel[kk]] * (1.f / (NH * NE));
            m = fmaxf(m, wv[kk]);
        }
        float sum = 0.f;
        for (int kk = 0; kk < TOPK; ++kk) { wv[kk] = expf(wv[kk] - m); sum += wv[kk]; }
        const float inv = 1.f / sum;
        for (int kk = 0; kk < TOPK; ++kk) ws_w[tid * 8 + kk] = wv[kk] * inv;
    }
}

// ---------------- Kernel C: lag-gather weighted sum of v ----------------
__global__ __launch_bounds__(256) void gather_kernel(
    const float* __restrict__ v, const int* __restrict__ ws_idx,
    const float* __restrict__ ws_w, float* __restrict__ out)
{
    const int n = blockIdx.y;
    const int idx4 = blockIdx.x * 256 + threadIdx.x;
    const int l = idx4 >> 7;
    const int r = idx4 & 127;
    const float* wrow = ws_w + n * 8;

    float4 acc = make_float4(0.f, 0.f, 0.f, 0.f);
#pragma unroll
    for (int kk = 0; kk < TOPK; ++kk) {
        const int t = (l + ws_idx[kk]) & (L_SEQ - 1);
        const float4 vv = *reinterpret_cast<const float4*>(
            v + (((size_t)n * L_SEQ + t) * (NH * NE)) + r * 4);
        const float wk = wrow[kk];
        acc.x = fmaf(wk, vv.x, acc.x);
        acc.y = fmaf(wk, vv.y, acc.y);
        acc.z = fmaf(wk, vv.z, acc.z);
        acc.w = fmaf(wk, vv.w, acc.w);
    }
    *reinterpret_cast<float4*>(out + ((size_t)n * L_SEQ + l) * (NH * NE) + r * 4) = acc;
}

extern "C" void kernel_launch(void* const* d_in, const int* in_sizes, int n_in,
                              void* d_out, int out_size, void* d_ws, size_t ws_size,
                              hipStream_t stream)
{
    const float* q = (const float*)d_in[0];
    const float* k = (const float*)d_in[1];
    const float* v = (const float*)d_in[2];
    float* out = (float*)d_out;
    float* corr_out = out + (size_t)NB * L_SEQ * NH * NE;

    float* ws_mean = (float*)d_ws;                              // 32*1024 f32
    int*   ws_idx  = (int*)((char*)d_ws + 131072);              // 6 ints
    float* ws_w    = (float*)((char*)d_ws + 131072 + 256);      // 32*8 f32

    hipMemsetAsync(d_ws, 0, 131072, stream);
    fftcorr_kernel<<<dim3(NE / 8, NH, NB), 512, LDS_BYTES, stream>>>(q, k, corr_out, ws_mean);
    topk_softmax_kernel<<<1, 1024, 0, stream>>>(ws_mean, ws_idx, ws_w);
    gather_kernel<<<dim3(512, NB), 256, 0, stream>>>(v, ws_idx, ws_w, out);
}

// Round 15
// 178.727 us; speedup vs baseline: 1.0671x; 1.0551x over previous
//
#include <hip/hip_runtime.h>
#include <hip/hip_fp16.h>

#define L_SEQ 1024
#define NB 32
#define NH 8
#define NE 64
#define TOPK 6

typedef unsigned int u32;

// LDS geometry (round 15): 16 fp16x2-packed complex series planes + fp32 table.
// Plane: 1024 packed complex (u32) as 32 groups of 32 at stride 36.
// 16*1152*4 + 544*4 = 75,904 B -> 2 blocks/CU; block = 1024 thr = 16 waves
// -> 32 waves/CU (hardware max). e-tile widened 8->16 so each staged row read
// is 64B aligned-contiguous: kills the 2x fetch waste (262 MB vs 128 MB
// compulsory) seen in rounds 7-14.
#define PSC  1152                 // u32 per packed series plane
#define TBOU (16 * PSC)           // table offset (u32 units)
#define PHYS(L)  (36 * ((L) >> 5) + ((L) & 31))
#define TPHYS(E) ((E) + ((E) >> 4))
#define LDS_BYTES ((TBOU + 544) * 4)   // 75,904 B

constexpr float K16C[4] = {1.f, 0.92387953f, 0.70710678f, 0.38268343f};
constexpr float K16S[4] = {0.f, 0.38268343f, 0.70710678f, 0.92387953f};

__device__ __forceinline__ u32 PK(float r, float i) {
    union { __half2 h; u32 u; } c;
    c.h = __floats2half2_rn(r, i);
    return c.u;
}
__device__ __forceinline__ float2 UPK(u32 u) {
    union { u32 u; __half2 h; } c;
    c.u = u;
    return __half22float2(c.h);
}
#define UQ4(Z,R,I) { const float2 a_=UPK(Z.x), b_=UPK(Z.y), c_=UPK(Z.z), d_=UPK(Z.w); \
    R = make_float4(a_.x,b_.x,c_.x,d_.x); I = make_float4(a_.y,b_.y,c_.y,d_.y); }
#define PQ4(Z,R,I) { Z.x=PK(R.x,I.x); Z.y=PK(R.y,I.y); Z.z=PK(R.z,I.z); Z.w=PK(R.w,I.w); }

#define BTF4F(A,B,C,D) { \
    const float t0r = xr##A + xr##C, t0i = xi##A + xi##C; \
    const float d2r = xr##A - xr##C, d2i = xi##A - xi##C; \
    const float t2r = d2r*w1r - d2i*w1i, t2i = d2i*w1r + d2r*w1i; \
    const float t1r = xr##B + xr##D, t1i = xi##B + xi##D; \
    const float d3r = xr##B - xr##D, d3i = xi##B - xi##D; \
    const float m3r = d3r*w1r - d3i*w1i, m3i = d3i*w1r + d3r*w1i; \
    const float t3r = m3i, t3i = -m3r; \
    const float a0r = t0r + t1r, a0i = t0i + t1i; \
    const float a1r = t0r - t1r, a1i = t0i - t1i; \
    const float a2r = t2r + t3r, a2i = t2i + t3i; \
    const float a3r = t2r - t3r, a3i = t2i - t3i; \
    xr##A = a0r; xi##A = a0i; \
    xr##B = a1r*w3r - a1i*w3i; xi##B = a1i*w3r + a1r*w3i; \
    xr##C = a2r; xi##C = a2i; \
    xr##D = a3r*w3r - a3i*w3i; xi##D = a3i*w3r + a3r*w3i; }

#define BTF4I(A,B,C,D) { \
    const float m1r = xr##B*w3r - xi##B*w3i, m1i = xi##B*w3r + xr##B*w3i; \
    const float s0r = xr##A + m1r, s0i = xi##A + m1i; \
    const float s1r = xr##A - m1r, s1i = xi##A - m1i; \
    const float m3r = xr##D*w3r - xi##D*w3i, m3i = xi##D*w3r + xr##D*w3i; \
    const float s2r = xr##C + m3r, s2i = xi##C + m3i; \
    const float s3r = xr##C - m3r, s3i = xi##C - m3i; \
    const float t2r = s2r*w1r - s2i*w1i, t2i = s2i*w1r + s2r*w1i; \
    const float n3r = s3r*w1r - s3i*w1i, n3i = s3i*w1r + s3r*w1i; \
    const float t3r = -n3i, t3i = n3r; \
    xr##A = s0r + t2r; xi##A = s0i + t2i; \
    xr##C = s0r - t2r; xi##C = s0i - t2i; \
    xr##B = s1r + t3r; xi##B = s1i + t3i; \
    xr##D = s1r - t3r; xi##D = s1i - t3i; }

// ---- head4: levels 1024,512,256,128 in one pass; lane owns {lane + 64j}.
__device__ __forceinline__ void head4_fwd(u32* __restrict__ pc,
                                          const float* __restrict__ tab, int lane)
{
    const int A0 = 36 * (lane >> 5) + (lane & 31);
    const float tc = tab[TPHYS(lane)];
    const float ts = tab[272 + TPHYS(lane)];
    const float wbr = tc, wbi = -ts;
    const float w2r = wbr*wbr - wbi*wbi, w2i = 2.f*wbr*wbi;
    const float w4r = w2r*w2r - w2i*w2i, w4i = 2.f*w2r*w2i;
    const float w8r = w4r*w4r - w4i*w4i, w8i = 2.f*w4r*w4i;
#define HD(J) float xr##J, xi##J; { const float2 z_ = UPK(pc[A0 + 72*J]); xr##J = z_.x; xi##J = z_.y; }
    HD(0) HD(1) HD(2) HD(3) HD(4) HD(5) HD(6) HD(7)
    HD(8) HD(9) HD(10) HD(11) HD(12) HD(13) HD(14) HD(15)
#undef HD
#define STA(JA,JB,JC,JD,J16) { \
    const float w1r = wbr*K16C[J16] + wbi*K16S[J16]; \
    const float w1i = wbi*K16C[J16] - wbr*K16S[J16]; \
    const float w3r = w1r*w1r - w1i*w1i, w3i = 2.f*w1r*w1i; \
    BTF4F(JA,JB,JC,JD) }
    STA(0,4,8,12,0) STA(1,5,9,13,1) STA(2,6,10,14,2) STA(3,7,11,15,3)
#undef STA
    {
        const float w1r = w4r, w1i = w4i, w3r = w8r, w3i = w8i;
        BTF4F(0,1,2,3) BTF4F(4,5,6,7) BTF4F(8,9,10,11) BTF4F(12,13,14,15)
    }
#define HS(J) pc[A0 + 72*J] = PK(xr##J, xi##J);
    HS(0) HS(1) HS(2) HS(3) HS(4) HS(5) HS(6) HS(7)
    HS(8) HS(9) HS(10) HS(11) HS(12) HS(13) HS(14) HS(15)
#undef HS
}

__device__ __forceinline__ void head4_inv(u32* __restrict__ pc,
                                          const float* __restrict__ tab, int lane)
{
    const int A0 = 36 * (lane >> 5) + (lane & 31);
    const float tc = tab[TPHYS(lane)];
    const float ts = tab[272 + TPHYS(lane)];
    const float vbr = tc, vbi = ts;
    const float v2r = vbr*vbr - vbi*vbi, v2i = 2.f*vbr*vbi;
    const float v4r = v2r*v2r - v2i*v2i, v4i = 2.f*v2r*v2i;
    const float v8r = v4r*v4r - v4i*v4i, v8i = 2.f*v4r*v4i;
#define HD(J) float xr##J, xi##J; { const float2 z_ = UPK(pc[A0 + 72*J]); xr##J = z_.x; xi##J = z_.y; }
    HD(0) HD(1) HD(2) HD(3) HD(4) HD(5) HD(6) HD(7)
    HD(8) HD(9) HD(10) HD(11) HD(12) HD(13) HD(14) HD(15)
#undef HD
    {
        const float w1r = v4r, w1i = v4i, w3r = v8r, w3i = v8i;
        BTF4I(0,1,2,3) BTF4I(4,5,6,7) BTF4I(8,9,10,11) BTF4I(12,13,14,15)
    }
#define STB(JA,JB,JC,JD,J16) { \
    const float w1r = vbr*K16C[J16] - vbi*K16S[J16]; \
    const float w1i = vbi*K16C[J16] + vbr*K16S[J16]; \
    const float w3r = w1r*w1r - w1i*w1i, w3i = 2.f*w1r*w1i; \
    BTF4I(JA,JB,JC,JD) }
    STB(0,4,8,12,0) STB(1,5,9,13,1) STB(2,6,10,14,2) STB(3,7,11,15,3)
#undef STB
#define HS(J) pc[A0 + 72*J] = PK(xr##J, xi##J);
    HS(0) HS(1) HS(2) HS(3) HS(4) HS(5) HS(6) HS(7)
    HS(8) HS(9) HS(10) HS(11) HS(12) HS(13) HS(14) HS(15)
#undef HS
}

// ---- mid stage (levels 64,32): packed-quad radix-4
__device__ __forceinline__ void dif_mid(u32* __restrict__ pc,
                                        const float* __restrict__ tab, int lane)
{
    const int b0 = lane << 2;
    const int u0 = b0 & 15;
    const int Lb = ((b0 >> 4) << 6) + u0;
    const int P0 = PHYS(Lb), P1 = PHYS(Lb + 16), P2 = PHYS(Lb + 32), P3 = PHYS(Lb + 48);
    uint4 z0 = *(const uint4*)(pc + P0), z1 = *(const uint4*)(pc + P1);
    uint4 z2 = *(const uint4*)(pc + P2), z3 = *(const uint4*)(pc + P3);
    float4 r0, i0, r1, i1, r2, i2, r3, i3;
    UQ4(z0, r0, i0) UQ4(z1, r1, i1) UQ4(z2, r2, i2) UQ4(z3, r3, i3)
#define CBTF(CMP, II) { \
    const int e1 = (u0 + II) << 4; \
    const float w1c = tab[TPHYS(e1)]; \
    const float w1s = tab[272 + TPHYS(e1)]; \
    const float w3c = w1c * w1c - w1s * w1s; \
    const float w3s = 2.f * w1c * w1s; \
    const float t0r = r0.CMP + r2.CMP, t0i = i0.CMP + i2.CMP; \
    const float d2r = r0.CMP - r2.CMP, d2i = i0.CMP - i2.CMP; \
    const float t2r = d2r * w1c + d2i * w1s, t2i = d2i * w1c - d2r * w1s; \
    const float t1r = r1.CMP + r3.CMP, t1i = i1.CMP + i3.CMP; \
    const float d3r = r1.CMP - r3.CMP, d3i = i1.CMP - i3.CMP; \
    const float m3r = d3r * w1c + d3i * w1s, m3i = d3i * w1c - d3r * w1s; \
    const float t3r = m3i, t3i = -m3r; \
    const float a0r = t0r + t1r, a0i = t0i + t1i; \
    const float a1r = t0r - t1r, a1i = t0i - t1i; \
    const float a2r = t2r + t3r, a2i = t2i + t3i; \
    const float a3r = t2r - t3r, a3i = t2i - t3i; \
    r0.CMP = a0r;                     i0.CMP = a0i; \
    r1.CMP = a1r * w3c + a1i * w3s;   i1.CMP = a1i * w3c - a1r * w3s; \
    r2.CMP = a2r;                     i2.CMP = a2i; \
    r3.CMP = a3r * w3c + a3i * w3s;   i3.CMP = a3i * w3c - a3r * w3s; }
    CBTF(x, 0) CBTF(y, 1) CBTF(z, 2) CBTF(w, 3)
#undef CBTF
    PQ4(z0, r0, i0) PQ4(z1, r1, i1) PQ4(z2, r2, i2) PQ4(z3, r3, i3)
    *(uint4*)(pc + P0) = z0; *(uint4*)(pc + P1) = z1;
    *(uint4*)(pc + P2) = z2; *(uint4*)(pc + P3) = z3;
}

__device__ __forceinline__ void dit_mid(u32* __restrict__ pc,
                                        const float* __restrict__ tab, int lane)
{
    const int b0 = lane << 2;
    const int u0 = b0 & 15;
    const int Lb = ((b0 >> 4) << 6) + u0;
    const int P0 = PHYS(Lb), P1 = PHYS(Lb + 16), P2 = PHYS(Lb + 32), P3 = PHYS(Lb + 48);
    uint4 z0 = *(const uint4*)(pc + P0), z1 = *(const uint4*)(pc + P1);
    uint4 z2 = *(const uint4*)(pc + P2), z3 = *(const uint4*)(pc + P3);
    float4 r0, i0, r1, i1, r2, i2, r3, i3;
    UQ4(z0, r0, i0) UQ4(z1, r1, i1) UQ4(z2, r2, i2) UQ4(z3, r3, i3)
#define CBTI(CMP, II) { \
    const int e1 = (u0 + II) << 4; \
    const float w1c = tab[TPHYS(e1)]; \
    const float w1s = tab[272 + TPHYS(e1)]; \
    const float w3c = w1c * w1c - w1s * w1s; \
    const float w3s = 2.f * w1c * w1s; \
    const float m1r = r1.CMP * w3c - i1.CMP * w3s, m1i = i1.CMP * w3c + r1.CMP * w3s; \
    const float s0r = r0.CMP + m1r, s0i = i0.CMP + m1i; \
    const float s1r = r0.CMP - m1r, s1i = i0.CMP - m1i; \
    const float m3r = r3.CMP * w3c - i3.CMP * w3s, m3i = i3.CMP * w3c + r3.CMP * w3s; \
    const float s2r = r2.CMP + m3r, s2i = i2.CMP + m3i; \
    const float s3r = r2.CMP - m3r, s3i = i2.CMP - m3i; \
    const float p2r = s2r * w1c - s2i * w1s, p2i = s2i * w1c + s2r * w1s; \
    const float n3r = s3r * w1c - s3i * w1s, n3i = s3i * w1c + s3r * w1s; \
    const float p3r = -n3i, p3i = n3r; \
    r0.CMP = s0r + p2r; i0.CMP = s0i + p2i; \
    r2.CMP = s0r - p2r; i2.CMP = s0i - p2i; \
    r1.CMP = s1r + p3r; i1.CMP = s1i + p3i; \
    r3.CMP = s1r - p3r; i3.CMP = s1i - p3i; }
    CBTI(x, 0) CBTI(y, 1) CBTI(z, 2) CBTI(w, 3)
#undef CBTI
    PQ4(z0, r0, i0) PQ4(z1, r1, i1) PQ4(z2, r2, i2) PQ4(z3, r3, i3)
    *(uint4*)(pc + P0) = z0; *(uint4*)(pc + P1) = z1;
    *(uint4*)(pc + P2) = z2; *(uint4*)(pc + P3) = z3;
}

// ---- tail_fused: levels 16..2 | S=Q*conj(K)/1024 | levels 2..16, one trip.
__device__ __forceinline__ void tail_fused(u32* __restrict__ pc, int lane)
{
    const int Pb = PHYS(lane << 4);
    uint4 z0 = *(const uint4*)(pc + Pb),     z1 = *(const uint4*)(pc + Pb + 4);
    uint4 z2 = *(const uint4*)(pc + Pb + 8), z3 = *(const uint4*)(pc + Pb + 12);
    float4 r0, i0, r1, i1, r2, i2, r3, i3;
    UQ4(z0, r0, i0) UQ4(z1, r1, i1) UQ4(z2, r2, i2) UQ4(z3, r3, i3)
#define TCF(CMP, C) { \
    const float w1r = K16C[C], w1i = -K16S[C]; \
    const float w3r = w1r*w1r - w1i*w1i, w3i = 2.f*w1r*w1i; \
    const float t0r = r0.CMP + r2.CMP, t0i = i0.CMP + i2.CMP; \
    const float d2r = r0.CMP - r2.CMP, d2i = i0.CMP - i2.CMP; \
    const float t2r = d2r*w1r - d2i*w1i, t2i = d2i*w1r + d2r*w1i; \
    const float t1r = r1.CMP + r3.CMP, t1i = i1.CMP + i3.CMP; \
    const float d3r = r1.CMP - r3.CMP, d3i = i1.CMP - i3.CMP; \
    const float m3r = d3r*w1r - d3i*w1i, m3i = d3i*w1r + d3r*w1i; \
    const float t3r = m3i, t3i = -m3r; \
    const float a0r = t0r+t1r, a0i = t0i+t1i; \
    const float a1r = t0r-t1r, a1i = t0i-t1i; \
    const float a2r = t2r+t3r, a2i = t2i+t3i; \
    const float a3r = t2r-t3r, a3i = t2i-t3i; \
    r0.CMP = a0r; i0.CMP = a0i; \
    r1.CMP = a1r*w3r - a1i*w3i; i1.CMP = a1i*w3r + a1r*w3i; \
    r2.CMP = a2r; i2.CMP = a2i; \
    r3.CMP = a3r*w3r - a3i*w3i; i3.CMP = a3i*w3r + a3r*w3i; }
    TCF(x,0) TCF(y,1) TCF(z,2) TCF(w,3)
#undef TCF
#define Q4F(RQ, IQ) { \
    const float t0r = RQ.x + RQ.z, t0i = IQ.x + IQ.z; \
    const float t2r = RQ.x - RQ.z, t2i = IQ.x - IQ.z; \
    const float t1r = RQ.y + RQ.w, t1i = IQ.y + IQ.w; \
    const float d3r = RQ.y - RQ.w, d3i = IQ.y - IQ.w; \
    const float t3r = d3i, t3i = -d3r; \
    RQ.x = t0r + t1r; IQ.x = t0i + t1i; \
    RQ.y = t0r - t1r; IQ.y = t0i - t1i; \
    RQ.z = t2r + t3r; IQ.z = t2i + t3i; \
    RQ.w = t2r - t3r; IQ.w = t2i - t3i; }
    Q4F(r0, i0) Q4F(r1, i1) Q4F(r2, i2) Q4F(r3, i3)
#undef Q4F
    PQ4(z0, r0, i0) PQ4(z1, r1, i1) PQ4(z2, r2, i2) PQ4(z3, r3, i3)
    *(uint4*)(pc + Pb) = z0;     *(uint4*)(pc + Pb + 4) = z1;
    *(uint4*)(pc + Pb + 8) = z2; *(uint4*)(pc + Pb + 12) = z3;
#define UNP(RQ, IQ, QI, CMP, JJ) { \
    const int p  = (lane << 4) + 4*QI + JJ; \
    const int f  = (int)(__brev((unsigned)p) >> 22); \
    const int fb = (1024 - f) & 1023; \
    const int pb = (int)(__brev((unsigned)fb) >> 22); \
    const float2 b_ = UPK(pc[PHYS(pb)]); \
    const float arv = RQ.CMP, aiv = IQ.CMP; \
    const float Qr = 0.5f*(arv + b_.x), Qi = 0.5f*(aiv - b_.y); \
    const float Kr = 0.5f*(aiv + b_.y), Ki = 0.5f*(b_.x - arv); \
    RQ.CMP = (Qr*Kr + Qi*Ki) * (1.f/1024.f); \
    IQ.CMP = (Qi*Kr - Qr*Ki) * (1.f/1024.f); }
    UNP(r0,i0,0,x,0) UNP(r0,i0,0,y,1) UNP(r0,i0,0,z,2) UNP(r0,i0,0,w,3)
    UNP(r1,i1,1,x,0) UNP(r1,i1,1,y,1) UNP(r1,i1,1,z,2) UNP(r1,i1,1,w,3)
    UNP(r2,i2,2,x,0) UNP(r2,i2,2,y,1) UNP(r2,i2,2,z,2) UNP(r2,i2,2,w,3)
    UNP(r3,i3,3,x,0) UNP(r3,i3,3,y,1) UNP(r3,i3,3,z,2) UNP(r3,i3,3,w,3)
#undef UNP
#define Q4I(RQ, IQ) { \
    const float s0r = RQ.x + RQ.y, s0i = IQ.x + IQ.y; \
    const float s1r = RQ.x - RQ.y, s1i = IQ.x - IQ.y; \
    const float s2r = RQ.z + RQ.w, s2i = IQ.z + IQ.w; \
    const float s3r = RQ.z - RQ.w, s3i = IQ.z - IQ.w; \
    const float p3r = -s3i, p3i = s3r; \
    RQ.x = s0r + s2r; IQ.x = s0i + s2i; \
    RQ.z = s0r - s2r; IQ.z = s0i - s2i; \
    RQ.y = s1r + p3r; IQ.y = s1i + p3i; \
    RQ.w = s1r - p3r; IQ.w = s1i - p3i; }
    Q4I(r0, i0) Q4I(r1, i1) Q4I(r2, i2) Q4I(r3, i3)
#undef Q4I
#define TCI(CMP, C) { \
    const float w1r = K16C[C], w1i = K16S[C]; \
    const float w3r = w1r*w1r - w1i*w1i, w3i = 2.f*w1r*w1i; \
    const float m1r = r1.CMP*w3r - i1.CMP*w3i, m1i = i1.CMP*w3r + r1.CMP*w3i; \
    const float s0r = r0.CMP + m1r, s0i = i0.CMP + m1i; \
    const float s1r = r0.CMP - m1r, s1i = i0.CMP - m1i; \
    const float m3r = r3.CMP*w3r - i3.CMP*w3i, m3i = i3.CMP*w3r + r3.CMP*w3i; \
    const float s2r = r2.CMP + m3r, s2i = i2.CMP + m3i; \
    const float s3r = r2.CMP - m3r, s3i = i2.CMP - m3i; \
    const float t2r = s2r*w1r - s2i*w1i, t2i = s2i*w1r + s2r*w1i; \
    const float n3r = s3r*w1r - s3i*w1i, n3i = s3i*w1r + s3r*w1i; \
    const float t3r = -n3i, t3i = n3r; \
    r0.CMP = s0r + t2r; i0.CMP = s0i + t2i; \
    r2.CMP = s0r - t2r; i2.CMP = s0i - t2i; \
    r1.CMP = s1r + t3r; i1.CMP = s1i + t3i; \
    r3.CMP = s1r - t3r; i3.CMP = s1i - t3i; }
    TCI(x,0) TCI(y,1) TCI(z,2) TCI(w,3)
#undef TCI
    PQ4(z0, r0, i0) PQ4(z1, r1, i1) PQ4(z2, r2, i2) PQ4(z3, r3, i3)
    *(uint4*)(pc + Pb) = z0;     *(uint4*)(pc + Pb + 4) = z1;
    *(uint4*)(pc + Pb + 8) = z2; *(uint4*)(pc + Pb + 12) = z3;
}

// ---------------- Kernel A: FFT autocorrelation ----------------
// grid (NE/16, NH, NB) = 1024 blocks; block 1024 thr = 16 waves; 16 series,
// one per wave. 2 blocks/CU -> 32 waves/CU.
__global__ __launch_bounds__(1024) void fftcorr_kernel(
    const float* __restrict__ q, const float* __restrict__ k,
    float* __restrict__ corr_out, float* __restrict__ ws_mean)
{
    extern __shared__ u32 LDSU[];
    float* tabf = (float*)(LDSU + TBOU);
    const int tid = threadIdx.x;
    const int n = blockIdx.z, h = blockIdx.y, e0 = blockIdx.x * 16;

    if (tid < 256) {
        float sv, cv;
        __sincosf((float)tid * (6.2831853071795865f / 1024.f), &sv, &cv);
        tabf[TPHYS(tid)] = cv;
        tabf[272 + TPHYS(tid)] = sv;
    }

    // staging: per (t): 16 e's = 64B contiguous per array (compulsory fetch)
    {
#pragma unroll
        for (int c = 0; c < 4; ++c) {
            const int idx = c * 1024 + tid;       // 0..4095
            const int eq = idx & 3;               // which float4 of 16 e's
            const int t  = idx >> 2;
            const size_t g = ((((size_t)n * L_SEQ + t) * NH + h) * NE) + e0 + 4 * eq;
            const float4 qv = *reinterpret_cast<const float4*>(q + g);
            const float4 kv = *reinterpret_cast<const float4*>(k + g);
            const int ph = PHYS(t);
            LDSU[(size_t)(4 * eq + 0) * PSC + ph] = PK(qv.x, kv.x);
            LDSU[(size_t)(4 * eq + 1) * PSC + ph] = PK(qv.y, kv.y);
            LDSU[(size_t)(4 * eq + 2) * PSC + ph] = PK(qv.z, kv.z);
            LDSU[(size_t)(4 * eq + 3) * PSC + ph] = PK(qv.w, kv.w);
        }
    }
    __syncthreads();

    const int w = tid >> 6;      // 0..15 — wave's series plane
    const int lane = tid & 63;

    {
        u32* pc = LDSU + (size_t)w * PSC;
        head4_fwd(pc, tabf, lane);
        dif_mid(pc, tabf, lane);
        tail_fused(pc, lane);
        dit_mid(pc, tabf, lane);
        head4_inv(pc, tabf, lane);
    }
    __syncthreads();

    // writeout: float4 across 4 planes' re-halves; 64B/row global writes
    {
#pragma unroll
        for (int c = 0; c < 4; ++c) {
            const int f4idx = c * 1024 + tid;     // 0..4095
            const int l  = f4idx >> 2;
            const int j4 = f4idx & 3;
            const int ph = PHYS(l);
            float4 v;
            v.x = UPK(LDSU[(size_t)(4 * j4 + 0) * PSC + ph]).x;
            v.y = UPK(LDSU[(size_t)(4 * j4 + 1) * PSC + ph]).x;
            v.z = UPK(LDSU[(size_t)(4 * j4 + 2) * PSC + ph]).x;
            v.w = UPK(LDSU[(size_t)(4 * j4 + 3) * PSC + ph]).x;
            *reinterpret_cast<float4*>(
                corr_out + ((((size_t)n * L_SEQ + l) * NH + h) * NE) + e0 + 4 * j4) = v;
            const float esum = v.x + v.y + v.z + v.w;
            float tot = esum + __shfl_xor(esum, 1, 64);
            tot += __shfl_xor(tot, 2, 64);
            if ((tid & 3) == 0) atomicAdd(&ws_mean[n * L_SEQ + l], tot);
        }
    }
}

// ---------------- Kernel B: top-6 lags + per-n softmax ----------------
__global__ __launch_bounds__(1024) void topk_softmax_kernel(
    const float* __restrict__ ws_mean, int* __restrict__ ws_idx,
    float* __restrict__ ws_w)
{
    __shared__ float val[1024];
    __shared__ float rv[1024];
    __shared__ int   ri[1024];
    __shared__ int   sel[TOPK];
    const int tid = threadIdx.x;

    float s = 0.f;
    for (int n = 0; n < NB; ++n) s += ws_mean[n * L_SEQ + tid];
    val[tid] = s;
    __syncthreads();

    for (int kk = 0; kk < TOPK; ++kk) {
        rv[tid] = val[tid];
        ri[tid] = tid;
        __syncthreads();
        for (int off = 512; off > 0; off >>= 1) {
            if (tid < off) {
                const float a = rv[tid], b = rv[tid + off];
                const int ia = ri[tid], ib = ri[tid + off];
                if (b > a || (b == a && ib < ia)) { rv[tid] = b; ri[tid] = ib; }
            }
            __syncthreads();
        }
        if (tid == 0) { sel[kk] = ri[0]; val[ri[0]] = -1e30f; }
        __syncthreads();
    }
    if (tid < TOPK) ws_idx[tid] = sel[tid];

    if (tid < NB) {
        float wv[TOPK];
        float m = -1e30f;
        for (int kk = 0; kk < TOPK; ++kk) {
            wv[kk] = ws_mean[tid * L_SEQ + sel[kk]] * (1.f / (NH * NE));
            m = fmaxf(m, wv[kk]);
        }
        float sum = 0.f;
        for (int kk = 0; kk < TOPK; ++kk) { wv[kk] = expf(wv[kk] - m); sum += wv[kk]; }
        const float inv = 1.f / sum;
        for (int kk = 0; kk < TOPK; ++kk) ws_w[tid * 8 + kk] = wv[kk] * inv;
    }
}

// ---------------- Kernel C: lag-gather weighted sum of v ----------------
__global__ __launch_bounds__(256) void gather_kernel(
    const float* __restrict__ v, const int* __restrict__ ws_idx,
    const float* __restrict__ ws_w, float* __restrict__ out)
{
    const int n = blockIdx.y;
    const int idx4 = blockIdx.x * 256 + threadIdx.x;
    const int l = idx4 >> 7;
    const int r = idx4 & 127;
    const float* wrow = ws_w + n * 8;

    float4 acc = make_float4(0.f, 0.f, 0.f, 0.f);
#pragma unroll
    for (int kk = 0; kk < TOPK; ++kk) {
        const int t = (l + ws_idx[kk]) & (L_SEQ - 1);
        const float4 vv = *reinterpret_cast<const float4*>(
            v + (((size_t)n * L_SEQ + t) * (NH * NE)) + r * 4);
        const float wk = wrow[kk];
        acc.x = fmaf(wk, vv.x, acc.x);
        acc.y = fmaf(wk, vv.y, acc.y);
        acc.z = fmaf(wk, vv.z, acc.z);
        acc.w = fmaf(wk, vv.w, acc.w);
    }
    *reinterpret_cast<float4*>(out + ((size_t)n * L_SEQ + l) * (NH * NE) + r * 4) = acc;
}

extern "C" void kernel_launch(void* const* d_in, const int* in_sizes, int n_in,
                              void* d_out, int out_size, void* d_ws, size_t ws_size,
                              hipStream_t stream)
{
    const float* q = (const float*)d_in[0];
    const float* k = (const float*)d_in[1];
    const float* v = (const float*)d_in[2];
    float* out = (float*)d_out;
    float* corr_out = out + (size_t)NB * L_SEQ * NH * NE;

    float* ws_mean = (float*)d_ws;                              // 32*1024 f32
    int*   ws_idx  = (int*)((char*)d_ws + 131072);              // 6 ints
    float* ws_w    = (float*)((char*)d_ws + 131072 + 256);      // 32*8 f32

    hipMemsetAsync(d_ws, 0, 131072, stream);
    fftcorr_kernel<<<dim3(NE / 16, NH, NB), 1024, LDS_BYTES, stream>>>(q, k, corr_out, ws_mean);
    topk_softmax_kernel<<<1, 1024, 0, stream>>>(ws_mean, ws_idx, ws_w);
    gather_kernel<<<dim3(512, NB), 256, 0, stream>>>(v, ws_idx, ws_w, out);
}